// Round 1
// baseline (6640.916 us; speedup 1.0000x reference)
//
#include <hip/hip_runtime.h>

// ---------------- problem constants ----------------
static const int N_NODES = 20000;
static const int N_EDGES = 320000;
static const int GDIM    = 256;   // input feature dim
static const int H1DIM   = 256;   // RGCN output dim
static const int C2DIM   = 512;   // HEADS * H2
static const int NREL    = 8;

// ---------------- fp32 tiled GEMM: C = A(MxK) @ B(KxN) + bias ----------------
#define BM 64
#define BN 64
#define BK 16

__global__ __launch_bounds__(256) void gemm_bias_k(
    const float* __restrict__ A, const float* __restrict__ B,
    const float* __restrict__ bias, float* __restrict__ C,
    int M, int N, int K)
{
  __shared__ float As[BK][BM];   // transposed A tile: As[k][m]
  __shared__ float Bs[BK][BN];
  const int tid  = threadIdx.x;
  const int brow = blockIdx.y * BM;
  const int bcol = blockIdx.x * BN;
  const int tr = (tid >> 4) * 4;   // 0..60
  const int tc = (tid & 15) * 4;   // 0..60
  float acc[4][4] = {};

  const int lr  = tid >> 2;        // 0..63   A row within tile
  const int lk  = (tid & 3) * 4;   // 0,4,8,12 A k
  const int bkr = tid >> 4;        // 0..15   B k row
  const int bc  = (tid & 15) * 4;  // 0..60   B col

  for (int k0 = 0; k0 < K; k0 += BK) {
    float4 av = make_float4(0.f, 0.f, 0.f, 0.f);
    int ar = brow + lr;
    if (ar < M) av = *(const float4*)(A + (size_t)ar * K + k0 + lk);
    As[lk + 0][lr] = av.x; As[lk + 1][lr] = av.y;
    As[lk + 2][lr] = av.z; As[lk + 3][lr] = av.w;
    float4 bv = *(const float4*)(B + (size_t)(k0 + bkr) * N + bcol + bc);
    Bs[bkr][bc + 0] = bv.x; Bs[bkr][bc + 1] = bv.y;
    Bs[bkr][bc + 2] = bv.z; Bs[bkr][bc + 3] = bv.w;
    __syncthreads();
#pragma unroll
    for (int kk = 0; kk < BK; ++kk) {
      float a0 = As[kk][tr + 0], a1 = As[kk][tr + 1], a2 = As[kk][tr + 2], a3 = As[kk][tr + 3];
      float b0 = Bs[kk][tc + 0], b1 = Bs[kk][tc + 1], b2 = Bs[kk][tc + 2], b3 = Bs[kk][tc + 3];
      acc[0][0] += a0 * b0; acc[0][1] += a0 * b1; acc[0][2] += a0 * b2; acc[0][3] += a0 * b3;
      acc[1][0] += a1 * b0; acc[1][1] += a1 * b1; acc[1][2] += a1 * b2; acc[1][3] += a1 * b3;
      acc[2][0] += a2 * b0; acc[2][1] += a2 * b1; acc[2][2] += a2 * b2; acc[2][3] += a2 * b3;
      acc[3][0] += a3 * b0; acc[3][1] += a3 * b1; acc[3][2] += a3 * b2; acc[3][3] += a3 * b3;
    }
    __syncthreads();
  }
  float b0 = 0.f, b1 = 0.f, b2 = 0.f, b3 = 0.f;
  if (bias) { b0 = bias[bcol + tc + 0]; b1 = bias[bcol + tc + 1];
              b2 = bias[bcol + tc + 2]; b3 = bias[bcol + tc + 3]; }
#pragma unroll
  for (int i = 0; i < 4; ++i) {
    int row = brow + tr + i;
    if (row >= M) break;
    float* cp = C + (size_t)row * N + bcol + tc;
    cp[0] = acc[i][0] + b0; cp[1] = acc[i][1] + b1;
    cp[2] = acc[i][2] + b2; cp[3] = acc[i][3] + b3;
  }
}

// ---------------- per-(dst,rel) edge counts ----------------
__global__ void count_k(const int* __restrict__ dst, const int* __restrict__ et,
                        float* __restrict__ cnt)
{
  int e = blockIdx.x * blockDim.x + threadIdx.x;
  if (e >= N_EDGES) return;
  atomicAdd(&cnt[dst[e] * NREL + et[e]], 1.0f);
}

// ---------------- RGCN scatter for one relation: h1[dst] += Yr[src]/cnt ----------------
__global__ __launch_bounds__(256) void rgcn_scatter_k(
    const float* __restrict__ Yr, const int* __restrict__ src,
    const int* __restrict__ dst, const int* __restrict__ et,
    const float* __restrict__ cnt, float* __restrict__ h1, int rel)
{
  int wid  = blockIdx.x * 4 + (threadIdx.x >> 6);
  int lane = threadIdx.x & 63;
  if (wid >= N_EDGES) return;
  if (et[wid] != rel) return;
  int s = src[wid], d = dst[wid];
  float inv = 1.0f / fmaxf(cnt[d * NREL + rel], 1.0f);
  float4 v = ((const float4*)(Yr + (size_t)s * H1DIM))[lane];
  float* hp = h1 + (size_t)d * H1DIM + lane * 4;
  atomicAdd(hp + 0, v.x * inv);
  atomicAdd(hp + 1, v.y * inv);
  atomicAdd(hp + 2, v.z * inv);
  atomicAdd(hp + 3, v.w * inv);
}

// ---------------- ordered-uint encoding for float atomicMax ----------------
__device__ inline unsigned int fenc(float f) {
  unsigned int b = __float_as_uint(f);
  return (b & 0x80000000u) ? ~b : (b | 0x80000000u);
}
__device__ inline float fdec(unsigned int u) {
  unsigned int b = (u & 0x80000000u) ? (u & 0x7fffffffu) : ~u;
  return __uint_as_float(b);
}

// ---------------- P1: alpha = (q[dst] . k[src]) * scale, segment max ----------------
__global__ __launch_bounds__(256) void attn_scores_k(
    const float* __restrict__ q, const float* __restrict__ k,
    const int* __restrict__ src, const int* __restrict__ dst,
    float* __restrict__ alpha, unsigned int* __restrict__ amax)
{
  int wid  = blockIdx.x * 4 + (threadIdx.x >> 6);
  int lane = threadIdx.x & 63;
  if (wid >= N_EDGES) return;
  int s = src[wid], d = dst[wid];
  const float4* qp = (const float4*)(q + (size_t)d * C2DIM);
  const float4* kp = (const float4*)(k + (size_t)s * C2DIM);
  float4 q0 = qp[lane * 2], q1 = qp[lane * 2 + 1];
  float4 k0 = kp[lane * 2], k1 = kp[lane * 2 + 1];
  float p = q0.x * k0.x + q0.y * k0.y + q0.z * k0.z + q0.w * k0.w
          + q1.x * k1.x + q1.y * k1.y + q1.z * k1.z + q1.w * k1.w;
  // reduce over each 16-lane group (one head = 128 floats = 16 lanes)
  p += __shfl_xor(p, 1);
  p += __shfl_xor(p, 2);
  p += __shfl_xor(p, 4);
  p += __shfl_xor(p, 8);
  if ((lane & 15) == 0) {
    int h = lane >> 4;
    float a = p * 0.08838834764831845f;   // 1/sqrt(128)
    alpha[(size_t)wid * 4 + h] = a;
    atomicMax(&amax[d * 4 + h], fenc(a));
  }
}

// ---------------- P2: ea = exp(alpha - amax[dst]), denom += ea ----------------
__global__ void attn_exp_k(float* __restrict__ ea,
                           const unsigned int* __restrict__ amax,
                           const int* __restrict__ dst,
                           float* __restrict__ denom)
{
  int i = blockIdx.x * blockDim.x + threadIdx.x;
  if (i >= N_EDGES * 4) return;
  int e = i >> 2, h = i & 3;
  int d = dst[e];
  float m = fdec(amax[d * 4 + h]);
  float v = expf(ea[i] - m);
  ea[i] = v;
  atomicAdd(&denom[d * 4 + h], v);
}

// ---------------- P3: out[dst] += (ea/denom) * v[src] ----------------
__global__ __launch_bounds__(256) void attn_out_k(
    const float* __restrict__ ea, const float* __restrict__ denom,
    const float* __restrict__ v, const int* __restrict__ src,
    const int* __restrict__ dst, float* __restrict__ out)
{
  int wid  = blockIdx.x * 4 + (threadIdx.x >> 6);
  int lane = threadIdx.x & 63;
  if (wid >= N_EDGES) return;
  int s = src[wid], d = dst[wid];
  int h = lane >> 4;
  float w = ea[(size_t)wid * 4 + h] / fmaxf(denom[d * 4 + h], 1e-16f);
  const float4* vp = (const float4*)(v + (size_t)s * C2DIM);
  float4 v0 = vp[lane * 2], v1 = vp[lane * 2 + 1];
  float* op = out + (size_t)d * C2DIM + lane * 8;
  atomicAdd(op + 0, v0.x * w);
  atomicAdd(op + 1, v0.y * w);
  atomicAdd(op + 2, v0.z * w);
  atomicAdd(op + 3, v0.w * w);
  atomicAdd(op + 4, v1.x * w);
  atomicAdd(op + 5, v1.y * w);
  atomicAdd(op + 6, v1.z * w);
  atomicAdd(op + 7, v1.w * w);
}

// ---------------- BN: column sums / sumsq ----------------
__global__ __launch_bounds__(512) void bn_stats_k(
    const float* __restrict__ x, float* __restrict__ sums, float* __restrict__ sumsq)
{
  int c = threadIdx.x;   // 0..511
  float s = 0.f, sq = 0.f;
  for (int row = blockIdx.x; row < N_NODES; row += gridDim.x) {
    float v = x[(size_t)row * C2DIM + c];
    s += v; sq += v * v;
  }
  atomicAdd(&sums[c], s);
  atomicAdd(&sumsq[c], sq);
}

__global__ void bn_final_k(const float* __restrict__ sums, const float* __restrict__ sumsq,
                           const float* __restrict__ gamma, const float* __restrict__ beta,
                           float* __restrict__ scale, float* __restrict__ shift)
{
  int c = threadIdx.x;
  float mu  = sums[c] * (1.0f / N_NODES);
  float var = sumsq[c] * (1.0f / N_NODES) - mu * mu;
  float sc  = gamma[c] * rsqrtf(var + 1e-5f);
  scale[c] = sc;
  shift[c] = beta[c] - mu * sc;
}

__global__ void bn_apply_k(const float* __restrict__ x, const float* __restrict__ scale,
                           const float* __restrict__ shift, float* __restrict__ out, int total)
{
  int i = blockIdx.x * blockDim.x + threadIdx.x;
  if (i >= total) return;
  int c = i & (C2DIM - 1);
  float v = x[i] * scale[c] + shift[c];
  out[i] = v >= 0.f ? v : 0.01f * v;
}

// ---------------- launch ----------------
extern "C" void kernel_launch(void* const* d_in, const int* in_sizes, int n_in,
                              void* d_out, int out_size, void* d_ws, size_t ws_size,
                              hipStream_t stream)
{
  const float* x      = (const float*)d_in[0];
  // d_in[1] node_type: unused by reference
  const int*   ei     = (const int*)d_in[2];
  const int*   src    = ei;
  const int*   dst    = ei + N_EDGES;
  const int*   etype  = (const int*)d_in[3];
  const float* W_rel  = (const float*)d_in[4];
  const float* W_root = (const float*)d_in[5];
  const float* b_rgcn = (const float*)d_in[6];
  const float* W_q = (const float*)d_in[7];  const float* b_q = (const float*)d_in[8];
  const float* W_k = (const float*)d_in[9];  const float* b_k = (const float*)d_in[10];
  const float* W_v = (const float*)d_in[11]; const float* b_v = (const float*)d_in[12];
  const float* W_s = (const float*)d_in[13]; const float* b_s = (const float*)d_in[14];
  const float* gamma = (const float*)d_in[15];
  const float* beta  = (const float*)d_in[16];
  float* out = (float*)d_out;

  // ---- workspace layout (bytes), total 108,808,192 ----
  char* ws = (char*)d_ws;
  float* h1    = (float*)(ws + 0);           // 20,480,000  (N x 256)
  float* buf1  = (float*)(ws + 20480000);    // 40,960,000  (k, then out-accum)
  float* buf2  = (float*)(ws + 61440000);    // 40,960,000  (Yr, then v)
  float* ea    = (float*)(ws + 102400000);   //  5,120,000  (alpha / ea, E x 4)
  float* cnt   = (float*)(ws + 107520000);   //    640,000  (N x R)
  unsigned int* amax = (unsigned int*)(ws + 108160000); // 320,000 (N x 4)
  float* denom = (float*)(ws + 108480000);   //    320,000  (N x 4)
  float* bns   = (float*)(ws + 108800000);   //      8,192
  float* bnsum = bns, *bnsq = bns + 512, *bnscale = bns + 1024, *bnshift = bns + 1536;
  float* q = out;   // q lives in d_out until P1 is done

  // zero the accumulator region (cnt..bns is contiguous)
  hipMemsetAsync(ws + 107520000, 0, 640000 + 320000 + 320000 + 8192, stream);

  dim3 blk(256);
  // per-(dst,rel) counts
  count_k<<<dim3((N_EDGES + 255) / 256), blk, 0, stream>>>(dst, etype, cnt);

  // h1 = x @ W_root + b_rgcn
  gemm_bias_k<<<dim3(H1DIM / BN, (N_NODES + BM - 1) / BM), blk, 0, stream>>>(
      x, W_root, b_rgcn, h1, N_NODES, H1DIM, GDIM);

  // RGCN: per relation, Yr = x @ W_rel[r]; h1[dst] += Yr[src]/cnt
  for (int r = 0; r < NREL; ++r) {
    gemm_bias_k<<<dim3(H1DIM / BN, (N_NODES + BM - 1) / BM), blk, 0, stream>>>(
        x, W_rel + (size_t)r * GDIM * H1DIM, nullptr, buf2, N_NODES, H1DIM, GDIM);
    rgcn_scatter_k<<<dim3((N_EDGES + 3) / 4), blk, 0, stream>>>(
        buf2, src, dst, etype, cnt, h1, r);
  }

  // q, k, v projections
  gemm_bias_k<<<dim3(C2DIM / BN, (N_NODES + BM - 1) / BM), blk, 0, stream>>>(
      h1, W_q, b_q, q, N_NODES, C2DIM, H1DIM);
  gemm_bias_k<<<dim3(C2DIM / BN, (N_NODES + BM - 1) / BM), blk, 0, stream>>>(
      h1, W_k, b_k, buf1, N_NODES, C2DIM, H1DIM);
  gemm_bias_k<<<dim3(C2DIM / BN, (N_NODES + BM - 1) / BM), blk, 0, stream>>>(
      h1, W_v, b_v, buf2, N_NODES, C2DIM, H1DIM);

  // P1: scores + segment max
  attn_scores_k<<<dim3((N_EDGES + 3) / 4), blk, 0, stream>>>(q, buf1, src, dst, ea, amax);
  // P2: exp + denom
  attn_exp_k<<<dim3((N_EDGES * 4 + 255) / 256), blk, 0, stream>>>(ea, amax, dst, denom);

  // out-accum = h1 @ W_skip + b_skip   (overwrites k; q no longer needed after P1)
  gemm_bias_k<<<dim3(C2DIM / BN, (N_NODES + BM - 1) / BM), blk, 0, stream>>>(
      h1, W_s, b_s, buf1, N_NODES, C2DIM, H1DIM);

  // P3: scatter attention-weighted v
  attn_out_k<<<dim3((N_EDGES + 3) / 4), blk, 0, stream>>>(ea, denom, buf2, src, dst, buf1);

  // BatchNorm + LeakyReLU
  bn_stats_k<<<dim3(208), dim3(512), 0, stream>>>(buf1, bnsum, bnsq);
  bn_final_k<<<dim3(1), dim3(512), 0, stream>>>(bnsum, bnsq, gamma, beta, bnscale, bnshift);
  bn_apply_k<<<dim3((N_NODES * C2DIM + 255) / 256), blk, 0, stream>>>(
      buf1, bnscale, bnshift, out, N_NODES * C2DIM);
}

// Round 2
// 1239.975 us; speedup vs baseline: 5.3557x; 5.3557x over previous
//
#include <hip/hip_runtime.h>

// ---------------- problem constants ----------------
static const int N_NODES = 20000;
static const int N_EDGES = 320000;
static const int GDIM    = 256;   // input feature dim
static const int H1DIM   = 256;   // RGCN output dim
static const int C2DIM   = 512;   // HEADS * H2
static const int NREL    = 8;

// ---------------- fp32 tiled GEMM: C (opt +=) A(MxK) @ B(KxN) + bias ----------------
#define BM 64
#define BN 64
#define BK 16

__global__ __launch_bounds__(256) void gemm_bias_k(
    const float* __restrict__ A, const float* __restrict__ B,
    const float* __restrict__ bias, float* __restrict__ C,
    int M, int N, int K, int accum)
{
  __shared__ float As[BK][BM];   // transposed A tile: As[k][m]
  __shared__ float Bs[BK][BN];
  const int tid  = threadIdx.x;
  const int brow = blockIdx.y * BM;
  const int bcol = blockIdx.x * BN;
  const int tr = (tid >> 4) * 4;
  const int tc = (tid & 15) * 4;
  float acc[4][4] = {};

  const int lr  = tid >> 2;        // A row within tile
  const int lk  = (tid & 3) * 4;   // A k
  const int bkr = tid >> 4;        // B k row
  const int bc  = (tid & 15) * 4;  // B col

  for (int k0 = 0; k0 < K; k0 += BK) {
    float4 av = make_float4(0.f, 0.f, 0.f, 0.f);
    int ar = brow + lr;
    if (ar < M) av = *(const float4*)(A + (size_t)ar * K + k0 + lk);
    As[lk + 0][lr] = av.x; As[lk + 1][lr] = av.y;
    As[lk + 2][lr] = av.z; As[lk + 3][lr] = av.w;
    float4 bv = *(const float4*)(B + (size_t)(k0 + bkr) * N + bcol + bc);
    Bs[bkr][bc + 0] = bv.x; Bs[bkr][bc + 1] = bv.y;
    Bs[bkr][bc + 2] = bv.z; Bs[bkr][bc + 3] = bv.w;
    __syncthreads();
#pragma unroll
    for (int kk = 0; kk < BK; ++kk) {
      float a0 = As[kk][tr + 0], a1 = As[kk][tr + 1], a2 = As[kk][tr + 2], a3 = As[kk][tr + 3];
      float b0 = Bs[kk][tc + 0], b1 = Bs[kk][tc + 1], b2 = Bs[kk][tc + 2], b3 = Bs[kk][tc + 3];
      acc[0][0] += a0 * b0; acc[0][1] += a0 * b1; acc[0][2] += a0 * b2; acc[0][3] += a0 * b3;
      acc[1][0] += a1 * b0; acc[1][1] += a1 * b1; acc[1][2] += a1 * b2; acc[1][3] += a1 * b3;
      acc[2][0] += a2 * b0; acc[2][1] += a2 * b1; acc[2][2] += a2 * b2; acc[2][3] += a2 * b3;
      acc[3][0] += a3 * b0; acc[3][1] += a3 * b1; acc[3][2] += a3 * b2; acc[3][3] += a3 * b3;
    }
    __syncthreads();
  }
  float b0 = 0.f, b1 = 0.f, b2 = 0.f, b3 = 0.f;
  if (bias) { b0 = bias[bcol + tc + 0]; b1 = bias[bcol + tc + 1];
              b2 = bias[bcol + tc + 2]; b3 = bias[bcol + tc + 3]; }
#pragma unroll
  for (int i = 0; i < 4; ++i) {
    int row = brow + tr + i;
    if (row >= M) break;
    float* cp = C + (size_t)row * N + bcol + tc;
    float c0 = accum ? cp[0] : 0.f, c1 = accum ? cp[1] : 0.f;
    float c2 = accum ? cp[2] : 0.f, c3 = accum ? cp[3] : 0.f;
    cp[0] = c0 + acc[i][0] + b0; cp[1] = c1 + acc[i][1] + b1;
    cp[2] = c2 + acc[i][2] + b2; cp[3] = c3 + acc[i][3] + b3;
  }
}

// ---------------- CSR build: histogram ----------------
__global__ void hist_k(const int* __restrict__ dst, const int* __restrict__ et,
                       int* __restrict__ h1c, int* __restrict__ h2c)
{
  int e = blockIdx.x * blockDim.x + threadIdx.x;
  if (e >= N_EDGES) return;
  atomicAdd(&h1c[dst[e]], 1);
  atomicAdd(&h2c[et[e] * N_NODES + dst[e]], 1);
}

// ---------------- hierarchical exclusive scan ----------------
__global__ __launch_bounds__(1024) void scan_local_k(
    const int* __restrict__ in, int* __restrict__ out, int* __restrict__ bsum, int n)
{
  __shared__ int s[1024];
  int gi = blockIdx.x * 1024 + threadIdx.x;
  int v = gi < n ? in[gi] : 0;
  s[threadIdx.x] = v; __syncthreads();
  for (int off = 1; off < 1024; off <<= 1) {
    int t = threadIdx.x >= off ? s[threadIdx.x - off] : 0;
    __syncthreads();
    s[threadIdx.x] += t;
    __syncthreads();
  }
  if (gi < n) out[gi] = s[threadIdx.x] - v;   // exclusive
  if (threadIdx.x == 1023) bsum[blockIdx.x] = s[1023];
}

__global__ __launch_bounds__(1024) void scan_small_k(int* __restrict__ bsum, int nb)
{
  __shared__ int s[1024];
  int v = threadIdx.x < nb ? bsum[threadIdx.x] : 0;
  s[threadIdx.x] = v; __syncthreads();
  for (int off = 1; off < 1024; off <<= 1) {
    int t = threadIdx.x >= off ? s[threadIdx.x - off] : 0;
    __syncthreads();
    s[threadIdx.x] += t;
    __syncthreads();
  }
  if (threadIdx.x < nb) bsum[threadIdx.x] = s[threadIdx.x] - v;  // exclusive
}

__global__ void scan_addoff_k(int* __restrict__ out, const int* __restrict__ bsum, int n)
{
  int gi = blockIdx.x * 1024 + threadIdx.x;
  if (gi < n) out[gi] += bsum[blockIdx.x];
}

// off totals + cursor copies
__global__ void initcur_k(const int* __restrict__ off1, const int* __restrict__ off2,
                          int* __restrict__ cur1, int* __restrict__ cur2)
{
  int i = blockIdx.x * blockDim.x + threadIdx.x;
  if (i < N_NODES) cur1[i] = off1[i];
  if (i < N_NODES * NREL) cur2[i] = off2[i];
  if (i == 0) {
    ((int*)off1)[N_NODES] = N_EDGES;
    ((int*)off2)[N_NODES * NREL] = N_EDGES;
  }
}

// ---------------- reorder: fill sorted src lists ----------------
__global__ void reorder_k(const int* __restrict__ src, const int* __restrict__ dst,
                          const int* __restrict__ et,
                          int* __restrict__ cur1, int* __restrict__ cur2,
                          int* __restrict__ esrcD, int* __restrict__ esrcRD)
{
  int e = blockIdx.x * blockDim.x + threadIdx.x;
  if (e >= N_EDGES) return;
  int s = src[e], d = dst[e], r = et[e];
  int p1 = atomicAdd(&cur1[d], 1);
  esrcD[p1] = s;
  int p2 = atomicAdd(&cur2[r * N_NODES + d], 1);
  esrcRD[p2] = s;
}

// ---------------- RGCN gather: Agg[d] = mean_{e in (d,rel)} x[src_e] ----------------
__global__ __launch_bounds__(256) void rgcn_gather_k(
    const float* __restrict__ x, const int* __restrict__ off2,
    const int* __restrict__ esrcRD, float* __restrict__ Agg, int rel)
{
  int d = blockIdx.x * 4 + (threadIdx.x >> 6);
  if (d >= N_NODES) return;
  int lane = threadIdx.x & 63;
  int seg = rel * N_NODES + d;
  int beg = off2[seg], end = off2[seg + 1];
  float4 acc = make_float4(0.f, 0.f, 0.f, 0.f);
  for (int e = beg; e < end; ++e) {
    int s = esrcRD[e];
    float4 xv = ((const float4*)(x + (size_t)s * GDIM))[lane];
    acc.x += xv.x; acc.y += xv.y; acc.z += xv.z; acc.w += xv.w;
  }
  float inv = (end > beg) ? 1.0f / (float)(end - beg) : 0.0f;
  acc.x *= inv; acc.y *= inv; acc.z *= inv; acc.w *= inv;
  ((float4*)(Agg + (size_t)d * GDIM))[lane] = acc;
}

// ---------------- fused attention: online softmax, gather, in-place over q ----------------
__global__ __launch_bounds__(256) void attn_fused_k(
    float* __restrict__ q, const float* __restrict__ k, const float* __restrict__ v,
    const int* __restrict__ off1, const int* __restrict__ esrcD)
{
  int d = blockIdx.x * 4 + (threadIdx.x >> 6);
  if (d >= N_NODES) return;
  int lane = threadIdx.x & 63;
  float4* qrow = (float4*)(q + (size_t)d * C2DIM);
  float4 q0 = qrow[lane * 2], q1 = qrow[lane * 2 + 1];
  float m = -3.4e38f, ssum = 0.f;
  float4 a0 = make_float4(0.f,0.f,0.f,0.f), a1 = make_float4(0.f,0.f,0.f,0.f);
  int beg = off1[d], end = off1[d + 1];
  for (int e = beg; e < end; ++e) {
    int s = esrcD[e];
    const float4* krow = (const float4*)(k + (size_t)s * C2DIM);
    float4 k0 = krow[lane * 2], k1 = krow[lane * 2 + 1];
    float p = q0.x*k0.x + q0.y*k0.y + q0.z*k0.z + q0.w*k0.w
            + q1.x*k1.x + q1.y*k1.y + q1.z*k1.z + q1.w*k1.w;
    p += __shfl_xor(p, 1); p += __shfl_xor(p, 2);
    p += __shfl_xor(p, 4); p += __shfl_xor(p, 8);
    float a = p * 0.08838834764831845f;   // 1/sqrt(128)
    float mn = fmaxf(m, a);
    float corr = __expf(m - mn);
    float w = __expf(a - mn);
    ssum = ssum * corr + w;
    const float4* vrow = (const float4*)(v + (size_t)s * C2DIM);
    float4 v0 = vrow[lane * 2], v1 = vrow[lane * 2 + 1];
    a0.x = a0.x*corr + w*v0.x; a0.y = a0.y*corr + w*v0.y;
    a0.z = a0.z*corr + w*v0.z; a0.w = a0.w*corr + w*v0.w;
    a1.x = a1.x*corr + w*v1.x; a1.y = a1.y*corr + w*v1.y;
    a1.z = a1.z*corr + w*v1.z; a1.w = a1.w*corr + w*v1.w;
    m = mn;
  }
  float inv = 1.0f / fmaxf(ssum, 1e-16f);
  a0.x *= inv; a0.y *= inv; a0.z *= inv; a0.w *= inv;
  a1.x *= inv; a1.y *= inv; a1.z *= inv; a1.w *= inv;
  qrow[lane * 2] = a0; qrow[lane * 2 + 1] = a1;
}

// ---------------- BN ----------------
__global__ __launch_bounds__(512) void bn_stats_k(
    const float* __restrict__ x, float* __restrict__ sums, float* __restrict__ sumsq)
{
  int c = threadIdx.x;
  float s = 0.f, sq = 0.f;
  for (int row = blockIdx.x; row < N_NODES; row += gridDim.x) {
    float v = x[(size_t)row * C2DIM + c];
    s += v; sq += v * v;
  }
  atomicAdd(&sums[c], s);
  atomicAdd(&sumsq[c], sq);
}

__global__ void bn_final_k(const float* __restrict__ sums, const float* __restrict__ sumsq,
                           const float* __restrict__ gamma, const float* __restrict__ beta,
                           float* __restrict__ scale, float* __restrict__ shift)
{
  int c = threadIdx.x;
  float mu  = sums[c] * (1.0f / N_NODES);
  float var = sumsq[c] * (1.0f / N_NODES) - mu * mu;
  float sc  = gamma[c] * rsqrtf(var + 1e-5f);
  scale[c] = sc;
  shift[c] = beta[c] - mu * sc;
}

__global__ void bn_apply_k(const float* __restrict__ x, const float* __restrict__ scale,
                           const float* __restrict__ shift, float* __restrict__ out, int total)
{
  int i = blockIdx.x * blockDim.x + threadIdx.x;
  if (i >= total) return;
  int c = i & (C2DIM - 1);
  float v = x[i] * scale[c] + shift[c];
  out[i] = v >= 0.f ? v : 0.01f * v;
}

// ---------------- launch ----------------
extern "C" void kernel_launch(void* const* d_in, const int* in_sizes, int n_in,
                              void* d_out, int out_size, void* d_ws, size_t ws_size,
                              hipStream_t stream)
{
  const float* x      = (const float*)d_in[0];
  const int*   ei     = (const int*)d_in[2];
  const int*   src    = ei;
  const int*   dst    = ei + N_EDGES;
  const int*   etype  = (const int*)d_in[3];
  const float* W_rel  = (const float*)d_in[4];
  const float* W_root = (const float*)d_in[5];
  const float* b_rgcn = (const float*)d_in[6];
  const float* W_q = (const float*)d_in[7];  const float* b_q = (const float*)d_in[8];
  const float* W_k = (const float*)d_in[9];  const float* b_k = (const float*)d_in[10];
  const float* W_v = (const float*)d_in[11]; const float* b_v = (const float*)d_in[12];
  const float* W_s = (const float*)d_in[13]; const float* b_s = (const float*)d_in[14];
  const float* gamma = (const float*)d_in[15];
  const float* beta  = (const float*)d_in[16];
  float* out = (float*)d_out;

  // ---- workspace layout ----
  char* ws = (char*)d_ws;
  float* h1   = (float*)(ws + 0);            // 20,480,000  N x 256
  float* qbuf = (float*)(ws + 20480000);     // 40,960,000  Agg_r (first 20.5MB) then q/attn/preBN
  float* kbuf = (float*)(ws + 61440000);     // 40,960,000  k
  float* vbuf = out;                          // v lives in d_out until BN apply
  float* Agg  = qbuf;

  char* C = ws + 102400000;                  // CSR area
  int* cur1   = (int*)(C + 0);               // 80,000   (hist1 first, then cursor)
  int* hist2  = (int*)(C + 80000);           // 640,000
  int* cur2   = (int*)(C + 720000);          // 640,000
  int* off1   = (int*)(C + 1360000);         // 80,004
  int* off2   = (int*)(C + 1440016);         // 640,004
  int* esrcD  = (int*)(C + 2080032);         // 1,280,000
  int* esrcRD = (int*)(C + 3360032);         // 1,280,000
  int* bsum   = (int*)(C + 4640032);         // 4,096
  float* bns  = (float*)(C + 4644128);       // 8,192
  float* bnsum = bns, *bnsq = bns + 512, *bnscale = bns + 1024, *bnshift = bns + 1536;

  // zero histograms (cur1 doubles as hist1) + BN accumulators
  hipMemsetAsync(C, 0, 720000, stream);
  hipMemsetAsync(bns, 0, 8192, stream);

  dim3 blk(256);
  const int NB1 = (N_NODES + 1023) / 1024;          // 20
  const int NB2 = (N_NODES * NREL + 1023) / 1024;   // 157

  // ---- CSR build ----
  hist_k<<<dim3((N_EDGES + 255) / 256), blk, 0, stream>>>(dst, etype, cur1, hist2);
  scan_local_k<<<dim3(NB1), dim3(1024), 0, stream>>>(cur1, off1, bsum, N_NODES);
  scan_small_k<<<dim3(1), dim3(1024), 0, stream>>>(bsum, NB1);
  scan_addoff_k<<<dim3(NB1), dim3(1024), 0, stream>>>(off1, bsum, N_NODES);
  scan_local_k<<<dim3(NB2), dim3(1024), 0, stream>>>(hist2, off2, bsum, N_NODES * NREL);
  scan_small_k<<<dim3(1), dim3(1024), 0, stream>>>(bsum, NB2);
  scan_addoff_k<<<dim3(NB2), dim3(1024), 0, stream>>>(off2, bsum, N_NODES * NREL);
  initcur_k<<<dim3((N_NODES * NREL + 255) / 256), blk, 0, stream>>>(off1, off2, cur1, cur2);
  reorder_k<<<dim3((N_EDGES + 255) / 256), blk, 0, stream>>>(
      src, dst, etype, cur1, cur2, esrcD, esrcRD);

  // ---- RGCN: h1 = x @ W_root + b, then += mean_r(x) @ W_rel[r] ----
  gemm_bias_k<<<dim3(H1DIM / BN, (N_NODES + BM - 1) / BM), blk, 0, stream>>>(
      x, W_root, b_rgcn, h1, N_NODES, H1DIM, GDIM, 0);
  for (int r = 0; r < NREL; ++r) {
    rgcn_gather_k<<<dim3((N_NODES + 3) / 4), blk, 0, stream>>>(x, off2, esrcRD, Agg, r);
    gemm_bias_k<<<dim3(H1DIM / BN, (N_NODES + BM - 1) / BM), blk, 0, stream>>>(
        Agg, W_rel + (size_t)r * GDIM * H1DIM, nullptr, h1, N_NODES, H1DIM, GDIM, 1);
  }

  // ---- q, k, v projections ----
  gemm_bias_k<<<dim3(C2DIM / BN, (N_NODES + BM - 1) / BM), blk, 0, stream>>>(
      h1, W_q, b_q, qbuf, N_NODES, C2DIM, H1DIM, 0);
  gemm_bias_k<<<dim3(C2DIM / BN, (N_NODES + BM - 1) / BM), blk, 0, stream>>>(
      h1, W_k, b_k, kbuf, N_NODES, C2DIM, H1DIM, 0);
  gemm_bias_k<<<dim3(C2DIM / BN, (N_NODES + BM - 1) / BM), blk, 0, stream>>>(
      h1, W_v, b_v, vbuf, N_NODES, C2DIM, H1DIM, 0);

  // ---- fused attention (writes attn output over q rows) ----
  attn_fused_k<<<dim3((N_NODES + 3) / 4), blk, 0, stream>>>(qbuf, kbuf, vbuf, off1, esrcD);

  // ---- skip projection accumulates into attention output ----
  gemm_bias_k<<<dim3(C2DIM / BN, (N_NODES + BM - 1) / BM), blk, 0, stream>>>(
      h1, W_s, b_s, qbuf, N_NODES, C2DIM, H1DIM, 1);

  // ---- BatchNorm + LeakyReLU ----
  bn_stats_k<<<dim3(208), dim3(512), 0, stream>>>(qbuf, bnsum, bnsq);
  bn_final_k<<<dim3(1), dim3(512), 0, stream>>>(bnsum, bnsq, gamma, beta, bnscale, bnshift);
  bn_apply_k<<<dim3((N_NODES * C2DIM + 255) / 256), blk, 0, stream>>>(
      qbuf, bnscale, bnshift, out, N_NODES * C2DIM);
}

// Round 4
// 475.207 us; speedup vs baseline: 13.9748x; 2.6093x over previous
//
#include <hip/hip_runtime.h>

// ---------------- problem constants ----------------
static const int N_NODES = 20000;
static const int N_EDGES = 320000;
static const int GDIM    = 256;   // input feature dim
static const int H1DIM   = 256;   // RGCN output dim
static const int C2DIM   = 512;   // HEADS * H2
static const int NREL    = 8;

typedef _Float16 __attribute__((ext_vector_type(8))) half8;
typedef _Float16 __attribute__((ext_vector_type(4))) half4;
typedef __attribute__((ext_vector_type(4))) float f32x4;

// ---------------- fp16 MFMA GEMM: C = A(MxK) @ Bt(NxK)^T + bias ----------------
// 128x128 tile, 4 waves (2x2), each wave 64x64 out, BK=64, XOR-swizzled LDS.
template<int OUT_HALF>
__global__ __launch_bounds__(256) void gemm_mfma_k(
    const _Float16* __restrict__ A, const _Float16* __restrict__ Bt,
    const float* __restrict__ bias, void* __restrict__ Cout,
    int M, int N, int K)
{
  __shared__ _Float16 As[128 * 64];
  __shared__ _Float16 Bs[128 * 64];
  const int tid  = threadIdx.x;
  const int wid  = tid >> 6, lane = tid & 63;
  const int wr   = wid >> 1, wc = wid & 1;
  const int brow = blockIdx.y * 128;
  const int bcol = blockIdx.x * 128;
  const int l15  = lane & 15, lhi = lane >> 4;
  const int srow = tid >> 3;     // 0..31 staging row base
  const int sch  = tid & 7;      // 0..7 chunk

  f32x4 acc[4][4] = {};

  for (int k0 = 0; k0 < K; k0 += 64) {
    __syncthreads();
#pragma unroll
    for (int p = 0; p < 4; ++p) {
      int row = p * 32 + srow;
      int gr  = brow + row;
      half8 av = {};
      if (gr < M) av = *(const half8*)(A + (size_t)gr * K + k0 + sch * 8);
      ((half8*)As)[row * 8 + (sch ^ (row & 7))] = av;
      half8 bv = *(const half8*)(Bt + (size_t)(bcol + row) * K + k0 + sch * 8);
      ((half8*)Bs)[row * 8 + (sch ^ (row & 7))] = bv;
    }
    __syncthreads();
#pragma unroll
    for (int kf = 0; kf < 2; ++kf) {
      int cc = kf * 4 + lhi;
      half8 af[4], bfr[4];
#pragma unroll
      for (int mi = 0; mi < 4; ++mi) {
        int row = wr * 64 + mi * 16 + l15;
        af[mi] = ((const half8*)As)[row * 8 + (cc ^ (row & 7))];
      }
#pragma unroll
      for (int ni = 0; ni < 4; ++ni) {
        int row = wc * 64 + ni * 16 + l15;
        bfr[ni] = ((const half8*)Bs)[row * 8 + (cc ^ (row & 7))];
      }
#pragma unroll
      for (int mi = 0; mi < 4; ++mi)
#pragma unroll
        for (int ni = 0; ni < 4; ++ni)
          acc[mi][ni] = __builtin_amdgcn_mfma_f32_16x16x32_f16(
              af[mi], bfr[ni], acc[mi][ni], 0, 0, 0);
    }
  }
  // epilogue: C/D frag: col = lane&15, row = (lane>>4)*4 + j  [m89-verified]
#pragma unroll
  for (int ni = 0; ni < 4; ++ni) {
    int col = bcol + wc * 64 + ni * 16 + l15;
    float bb = bias ? bias[col] : 0.f;
#pragma unroll
    for (int mi = 0; mi < 4; ++mi) {
      int row0 = brow + wr * 64 + mi * 16 + lhi * 4;
#pragma unroll
      for (int j = 0; j < 4; ++j) {
        int r = row0 + j;
        if (r >= M) continue;
        float val = acc[mi][ni][j] + bb;
        if (OUT_HALF) ((_Float16*)Cout)[(size_t)r * N + col] = (_Float16)val;
        else          ((float*)Cout)[(size_t)r * N + col] = val;
      }
    }
  }
}

// ---------------- weight conversion / transpose to fp16 ----------------
// Wt_cat (256 rows n, 2304 cols k): k<256 -> W_root[k][n]; else W_rel[(k-256)][n]
__global__ void conv_wcat_k(const float* __restrict__ W_root, const float* __restrict__ W_rel,
                            _Float16* __restrict__ Wt)
{
  int k = blockIdx.x * 256 + threadIdx.x;   // 0..2303
  int n = blockIdx.y;                        // 0..255
  float v = (k < 256) ? W_root[(size_t)k * H1DIM + n]
                      : W_rel[(size_t)(k - 256) * H1DIM + n];
  Wt[(size_t)n * 2304 + k] = (_Float16)v;
}

// Wt_qkvs (2048 rows n, 256 cols k): n>>9 selects q/k/v/skip, c=n&511
__global__ void conv_wqkvs_k(const float* __restrict__ Wq, const float* __restrict__ Wk,
                             const float* __restrict__ Wv, const float* __restrict__ Ws,
                             _Float16* __restrict__ Wt)
{
  int k = threadIdx.x;           // 0..255
  int n = blockIdx.y;            // 0..2047
  int sel = n >> 9, c = n & 511;
  const float* W = sel == 0 ? Wq : sel == 1 ? Wk : sel == 2 ? Wv : Ws;
  Wt[(size_t)n * 256 + k] = (_Float16)W[(size_t)k * C2DIM + c];
}

// ---------------- CSR build ----------------
__global__ void hist_k(const int* __restrict__ dst, const int* __restrict__ et,
                       int* __restrict__ h1c, int* __restrict__ h2c)
{
  int e = blockIdx.x * blockDim.x + threadIdx.x;
  if (e >= N_EDGES) return;
  atomicAdd(&h1c[dst[e]], 1);
  atomicAdd(&h2c[et[e] * N_NODES + dst[e]], 1);
}

__global__ __launch_bounds__(1024) void scan_local_k(
    const int* __restrict__ in, int* __restrict__ out, int* __restrict__ bsum, int n)
{
  __shared__ int s[1024];
  int gi = blockIdx.x * 1024 + threadIdx.x;
  int v = gi < n ? in[gi] : 0;
  s[threadIdx.x] = v; __syncthreads();
  for (int off = 1; off < 1024; off <<= 1) {
    int t = threadIdx.x >= off ? s[threadIdx.x - off] : 0;
    __syncthreads();
    s[threadIdx.x] += t;
    __syncthreads();
  }
  if (gi < n) out[gi] = s[threadIdx.x] - v;
  if (threadIdx.x == 1023) bsum[blockIdx.x] = s[1023];
}

__global__ __launch_bounds__(1024) void scan_small_k(int* __restrict__ bsum, int nb)
{
  __shared__ int s[1024];
  int v = threadIdx.x < nb ? bsum[threadIdx.x] : 0;
  s[threadIdx.x] = v; __syncthreads();
  for (int off = 1; off < 1024; off <<= 1) {
    int t = threadIdx.x >= off ? s[threadIdx.x - off] : 0;
    __syncthreads();
    s[threadIdx.x] += t;
    __syncthreads();
  }
  if (threadIdx.x < nb) bsum[threadIdx.x] = s[threadIdx.x] - v;
}

__global__ void scan_addoff_k(int* __restrict__ out, const int* __restrict__ bsum, int n)
{
  int gi = blockIdx.x * 1024 + threadIdx.x;
  if (gi < n) out[gi] += bsum[blockIdx.x];
}

__global__ void initcur_k(const int* __restrict__ off1, const int* __restrict__ off2,
                          int* __restrict__ cur1, int* __restrict__ cur2)
{
  int i = blockIdx.x * blockDim.x + threadIdx.x;
  if (i < N_NODES) cur1[i] = off1[i];
  if (i < N_NODES * NREL) cur2[i] = off2[i];
  if (i == 0) {
    ((int*)off1)[N_NODES] = N_EDGES;
    ((int*)off2)[N_NODES * NREL] = N_EDGES;
  }
}

__global__ void reorder_k(const int* __restrict__ src, const int* __restrict__ dst,
                          const int* __restrict__ et,
                          int* __restrict__ cur1, int* __restrict__ cur2,
                          int* __restrict__ esrcD, int* __restrict__ esrcRD)
{
  int e = blockIdx.x * blockDim.x + threadIdx.x;
  if (e >= N_EDGES) return;
  int s = src[e], d = dst[e], r = et[e];
  esrcD[atomicAdd(&cur1[d], 1)] = s;
  esrcRD[atomicAdd(&cur2[r * N_NODES + d], 1)] = s;
}

// ---------------- build Xcat = [x | mean_r(x)] in fp16 ----------------
__global__ __launch_bounds__(256) void agg_xcat_k(
    const float* __restrict__ x, const int* __restrict__ off2,
    const int* __restrict__ esrcRD, _Float16* __restrict__ Xcat)
{
  int d = blockIdx.x * 4 + (threadIdx.x >> 6);
  if (d >= N_NODES) return;
  int lane = threadIdx.x & 63;
  _Float16* xrow = Xcat + (size_t)d * 2304;
  // copy own features
  float4 xv = ((const float4*)(x + (size_t)d * GDIM))[lane];
  half4 o;
  o.x = (_Float16)xv.x; o.y = (_Float16)xv.y;
  o.z = (_Float16)xv.z; o.w = (_Float16)xv.w;
  *(half4*)(xrow + lane * 4) = o;
  // per-relation means
  for (int r = 0; r < NREL; ++r) {
    int seg = r * N_NODES + d;
    int beg = off2[seg], end = off2[seg + 1];
    float4 acc = make_float4(0.f, 0.f, 0.f, 0.f);
    for (int e = beg; e < end; ++e) {
      int s = esrcRD[e];
      float4 v = ((const float4*)(x + (size_t)s * GDIM))[lane];
      acc.x += v.x; acc.y += v.y; acc.z += v.z; acc.w += v.w;
    }
    float inv = (end > beg) ? 1.0f / (float)(end - beg) : 0.0f;
    o.x = (_Float16)(acc.x * inv); o.y = (_Float16)(acc.y * inv);
    o.z = (_Float16)(acc.z * inv); o.w = (_Float16)(acc.w * inv);
    *(half4*)(xrow + 256 + r * 256 + lane * 4) = o;
  }
}

// ---------------- fused attention: fp32 q, fp16 k/v, adds into out (skip) ----------------
__global__ __launch_bounds__(256) void attn_fused_k(
    const float* __restrict__ q, const _Float16* __restrict__ kb,
    const _Float16* __restrict__ vb,
    const int* __restrict__ off1, const int* __restrict__ esrcD,
    float* __restrict__ out)
{
  int d = blockIdx.x * 4 + (threadIdx.x >> 6);
  if (d >= N_NODES) return;
  int lane = threadIdx.x & 63;
  const float4* qrow = (const float4*)(q + (size_t)d * C2DIM);
  float4 q0 = qrow[lane * 2], q1 = qrow[lane * 2 + 1];
  float qf[8] = {q0.x, q0.y, q0.z, q0.w, q1.x, q1.y, q1.z, q1.w};
  float m = -3.4e38f, ssum = 0.f;
  float av[8] = {};
  int beg = off1[d], end = off1[d + 1];
  for (int e = beg; e < end; ++e) {
    int s = esrcD[e];
    half8 kr = ((const half8*)(kb + (size_t)s * C2DIM))[lane];
    float p = 0.f;
#pragma unroll
    for (int j = 0; j < 8; ++j) p += qf[j] * (float)kr[j];
    p += __shfl_xor(p, 1); p += __shfl_xor(p, 2);
    p += __shfl_xor(p, 4); p += __shfl_xor(p, 8);
    float a = p * 0.08838834764831845f;   // 1/sqrt(128)
    float mn = fmaxf(m, a);
    float corr = __expf(m - mn), w = __expf(a - mn);
    ssum = ssum * corr + w;
    half8 vr = ((const half8*)(vb + (size_t)s * C2DIM))[lane];
#pragma unroll
    for (int j = 0; j < 8; ++j) av[j] = av[j] * corr + w * (float)vr[j];
    m = mn;
  }
  float inv = 1.0f / fmaxf(ssum, 1e-16f);
  float* orow = out + (size_t)d * C2DIM + lane * 8;
#pragma unroll
  for (int j = 0; j < 8; ++j) orow[j] += av[j] * inv;
}

// ---------------- BN ----------------
__global__ __launch_bounds__(512) void bn_stats_k(
    const float* __restrict__ x, float* __restrict__ sums, float* __restrict__ sumsq)
{
  int c = threadIdx.x;
  float s = 0.f, sq = 0.f;
  for (int row = blockIdx.x; row < N_NODES; row += gridDim.x) {
    float v = x[(size_t)row * C2DIM + c];
    s += v; sq += v * v;
  }
  atomicAdd(&sums[c], s);
  atomicAdd(&sumsq[c], sq);
}

__global__ void bn_final_k(const float* __restrict__ sums, const float* __restrict__ sumsq,
                           const float* __restrict__ gamma, const float* __restrict__ beta,
                           float* __restrict__ scale, float* __restrict__ shift)
{
  int c = threadIdx.x;
  float mu  = sums[c] * (1.0f / N_NODES);
  float var = sumsq[c] * (1.0f / N_NODES) - mu * mu;
  float sc  = gamma[c] * rsqrtf(var + 1e-5f);
  scale[c] = sc;
  shift[c] = beta[c] - mu * sc;
}

__global__ void bn_apply_k(float* __restrict__ x, const float* __restrict__ scale,
                           const float* __restrict__ shift, int total)
{
  int i = blockIdx.x * blockDim.x + threadIdx.x;
  if (i >= total) return;
  int c = i & (C2DIM - 1);
  float v = x[i] * scale[c] + shift[c];
  x[i] = v >= 0.f ? v : 0.01f * v;
}

// ---------------- launch ----------------
extern "C" void kernel_launch(void* const* d_in, const int* in_sizes, int n_in,
                              void* d_out, int out_size, void* d_ws, size_t ws_size,
                              hipStream_t stream)
{
  const float* x      = (const float*)d_in[0];
  const int*   ei     = (const int*)d_in[2];
  const int*   src    = ei;
  const int*   dst    = ei + N_EDGES;
  const int*   etype  = (const int*)d_in[3];
  const float* W_rel  = (const float*)d_in[4];
  const float* W_root = (const float*)d_in[5];
  const float* b_rgcn = (const float*)d_in[6];
  const float* W_q = (const float*)d_in[7];  const float* b_q = (const float*)d_in[8];
  const float* W_k = (const float*)d_in[9];  const float* b_k = (const float*)d_in[10];
  const float* W_v = (const float*)d_in[11]; const float* b_v = (const float*)d_in[12];
  const float* W_s = (const float*)d_in[13]; const float* b_s = (const float*)d_in[14];
  const float* gamma = (const float*)d_in[15];
  const float* beta  = (const float*)d_in[16];
  float* out = (float*)d_out;

  // ---- workspace layout (total 108,640,544 <= proven-safe budget) ----
  char* ws = (char*)d_ws;
  _Float16* Xcat   = (_Float16*)(ws + 0);          // N x 2304 fp16 = 92,160,000
  float*    qbuf   = (float*)(ws + 0);             // reuse: q fp32 (40.96 MB)
  _Float16* kbuf   = (_Float16*)(ws + 40960000);   // reuse: k fp16 (20.48 MB)
  _Float16* vbuf   = (_Float16*)(ws + 61440000);   // reuse: v fp16 (20.48 MB)
  _Float16* Wt_cat = (_Float16*)(ws + 92160000);   // 256 x 2304 fp16 = 1,179,648
  _Float16* Wt_qk  = (_Float16*)(ws + 93339648);   // 2048 x 256 fp16 = 1,048,576
  _Float16* h1h    = (_Float16*)(ws + 94388224);   // N x 256 fp16 = 10,240,000

  char* C = ws + 104628224;                  // CSR area
  int* cur1   = (int*)(C + 0);               // 80,000   (hist1, then cursor)
  int* cur2   = (int*)(C + 80000);           // 640,000  (hist2, then cursor)
  int* off1   = (int*)(C + 720000);          // 80,016
  int* off2   = (int*)(C + 800016);          // 640,016
  int* esrcD  = (int*)(C + 1440032);         // 1,280,000
  int* esrcRD = (int*)(C + 2720032);         // 1,280,000
  int* bsum   = (int*)(C + 4000032);         // 4,096
  float* bns  = (float*)(C + 4004128);       // 8,192
  float* bnsum = bns, *bnsq = bns + 512, *bnscale = bns + 1024, *bnshift = bns + 1536;

  hipMemsetAsync(C, 0, 720000, stream);      // hist1 + hist2
  hipMemsetAsync(bns, 0, 8192, stream);

  dim3 blk(256);
  const int NB1 = (N_NODES + 1023) / 1024;          // 20
  const int NB2 = (N_NODES * NREL + 1023) / 1024;   // 157

  // ---- CSR build ----
  hist_k<<<dim3((N_EDGES + 255) / 256), blk, 0, stream>>>(dst, etype, cur1, cur2);
  scan_local_k<<<dim3(NB1), dim3(1024), 0, stream>>>(cur1, off1, bsum, N_NODES);
  scan_small_k<<<dim3(1), dim3(1024), 0, stream>>>(bsum, NB1);
  scan_addoff_k<<<dim3(NB1), dim3(1024), 0, stream>>>(off1, bsum, N_NODES);
  scan_local_k<<<dim3(NB2), dim3(1024), 0, stream>>>(cur2, off2, bsum, N_NODES * NREL);
  scan_small_k<<<dim3(1), dim3(1024), 0, stream>>>(bsum, NB2);
  scan_addoff_k<<<dim3(NB2), dim3(1024), 0, stream>>>(off2, bsum, N_NODES * NREL);
  initcur_k<<<dim3((N_NODES * NREL + 255) / 256), blk, 0, stream>>>(off1, off2, cur1, cur2);
  reorder_k<<<dim3((N_EDGES + 255) / 256), blk, 0, stream>>>(
      src, dst, etype, cur1, cur2, esrcD, esrcRD);

  // ---- weight conversion (fp16, transposed) ----
  conv_wcat_k<<<dim3(9, 256), blk, 0, stream>>>(W_root, W_rel, Wt_cat);
  conv_wqkvs_k<<<dim3(1, 2048), blk, 0, stream>>>(W_q, W_k, W_v, W_s, Wt_qk);

  // ---- Xcat = [x | mean_r(x)] ----
  agg_xcat_k<<<dim3((N_NODES + 3) / 4), blk, 0, stream>>>(x, off2, esrcRD, Xcat);

  // ---- h1 (fp16) = Xcat @ Wcat + b_rgcn : one K=2304 GEMM ----
  gemm_mfma_k<1><<<dim3(H1DIM / 128, (N_NODES + 127) / 128), blk, 0, stream>>>(
      Xcat, Wt_cat, b_rgcn, h1h, N_NODES, H1DIM, 2304);

  // ---- q (fp32), k (fp16), v (fp16), skip (fp32 -> d_out) ----
  gemm_mfma_k<0><<<dim3(C2DIM / 128, (N_NODES + 127) / 128), blk, 0, stream>>>(
      h1h, Wt_qk + 0 * 512 * 256, b_q, qbuf, N_NODES, C2DIM, H1DIM);
  gemm_mfma_k<1><<<dim3(C2DIM / 128, (N_NODES + 127) / 128), blk, 0, stream>>>(
      h1h, Wt_qk + 1 * 512 * 256, b_k, kbuf, N_NODES, C2DIM, H1DIM);
  gemm_mfma_k<1><<<dim3(C2DIM / 128, (N_NODES + 127) / 128), blk, 0, stream>>>(
      h1h, Wt_qk + 2 * 512 * 256, b_v, vbuf, N_NODES, C2DIM, H1DIM);
  gemm_mfma_k<0><<<dim3(C2DIM / 128, (N_NODES + 127) / 128), blk, 0, stream>>>(
      h1h, Wt_qk + 3 * 512 * 256, b_s, out, N_NODES, C2DIM, H1DIM);

  // ---- fused attention adds into d_out (on top of skip) ----
  attn_fused_k<<<dim3((N_NODES + 3) / 4), blk, 0, stream>>>(
      qbuf, kbuf, vbuf, off1, esrcD, out);

  // ---- BatchNorm + LeakyReLU (in place on d_out) ----
  bn_stats_k<<<dim3(208), dim3(512), 0, stream>>>(out, bnsum, bnsq);
  bn_final_k<<<dim3(1), dim3(512), 0, stream>>>(bnsum, bnsq, gamma, beta, bnscale, bnshift);
  bn_apply_k<<<dim3((N_NODES * C2DIM + 255) / 256), blk, 0, stream>>>(
      out, bnscale, bnshift, N_NODES * C2DIM);
}

// Round 5
// 442.069 us; speedup vs baseline: 15.0223x; 1.0750x over previous
//
#include <hip/hip_runtime.h>

// ---------------- problem constants ----------------
static const int N_NODES = 20000;
static const int N_EDGES = 320000;
static const int GDIM    = 256;   // input feature dim
static const int H1DIM   = 256;   // RGCN output dim
static const int C2DIM   = 512;   // HEADS * H2
static const int NREL    = 8;

typedef _Float16 __attribute__((ext_vector_type(8))) half8;
typedef _Float16 __attribute__((ext_vector_type(4))) half4;
typedef __attribute__((ext_vector_type(4))) float f32x4;

__device__ __forceinline__ void gload_lds16(const void* g, void* l) {
  __builtin_amdgcn_global_load_lds(
      (const __attribute__((address_space(1))) unsigned int*)g,
      (__attribute__((address_space(3))) unsigned int*)l, 16, 0, 0);
}

// ---------------- fp16 MFMA GEMM: C = A(MxK) @ Bt(NxK)^T + bias ----------------
// 128x128 tile, 4 waves (2x2), each wave 64x64 out, BK=64.
// Staging: global_load_lds dwordx4, LINEAR LDS dest + pre-swizzled global source
// (chunk c ^= row&7); reads use the same XOR -> involution cancels (rule 21).
// A-tile boundary rows (row >= M) read in-workspace garbage; their MFMA output
// rows are independent and discarded by the masked epilogue.
template<int OUT_HALF>
__global__ __launch_bounds__(256) void gemm_mfma_k(
    const _Float16* __restrict__ A, const _Float16* __restrict__ Bt,
    const float* __restrict__ bias, void* __restrict__ Cout,
    int M, int N, int K)
{
  __shared__ _Float16 As[128 * 64];
  __shared__ _Float16 Bs[128 * 64];
  const int tid  = threadIdx.x;
  const int wid  = tid >> 6, lane = tid & 63;
  const int wr   = wid >> 1, wc = wid & 1;
  const int brow = blockIdx.y * 128;
  const int bcol = blockIdx.x * 128;
  const int l15  = lane & 15, lhi = lane >> 4;
  const int srow = wid * 32;          // wave's 32-row staging span
  const int lrow = lane >> 3;         // 0..7 row within one 8-row issue
  const int lchk = lane & 7;          // 0..7 16B chunk

  f32x4 acc[4][4] = {};

  for (int k0 = 0; k0 < K; k0 += 64) {
    __syncthreads();
#pragma unroll
    for (int i = 0; i < 4; ++i) {
      int row = srow + i * 8 + lrow;        // tile row 0..127
      int gc  = lchk ^ (row & 7);           // pre-swizzled source chunk
      gload_lds16(A  + (size_t)(brow + row) * K + k0 + gc * 8,
                  &As[(srow + i * 8) * 64]);
      gload_lds16(Bt + (size_t)(bcol + row) * K + k0 + gc * 8,
                  &Bs[(srow + i * 8) * 64]);
    }
    __syncthreads();
#pragma unroll
    for (int kf = 0; kf < 2; ++kf) {
      int cc = kf * 4 + lhi;
      half8 af[4], bfr[4];
#pragma unroll
      for (int mi = 0; mi < 4; ++mi) {
        int row = wr * 64 + mi * 16 + l15;
        af[mi] = ((const half8*)As)[row * 8 + (cc ^ (row & 7))];
      }
#pragma unroll
      for (int ni = 0; ni < 4; ++ni) {
        int row = wc * 64 + ni * 16 + l15;
        bfr[ni] = ((const half8*)Bs)[row * 8 + (cc ^ (row & 7))];
      }
#pragma unroll
      for (int mi = 0; mi < 4; ++mi)
#pragma unroll
        for (int ni = 0; ni < 4; ++ni)
          acc[mi][ni] = __builtin_amdgcn_mfma_f32_16x16x32_f16(
              af[mi], bfr[ni], acc[mi][ni], 0, 0, 0);
    }
  }
  // epilogue: C/D frag: col = lane&15, row = (lane>>4)*4 + j  [m89-verified]
#pragma unroll
  for (int ni = 0; ni < 4; ++ni) {
    int col = bcol + wc * 64 + ni * 16 + l15;
    float bb = bias ? bias[col] : 0.f;
#pragma unroll
    for (int mi = 0; mi < 4; ++mi) {
      int row0 = brow + wr * 64 + mi * 16 + lhi * 4;
#pragma unroll
      for (int j = 0; j < 4; ++j) {
        int r = row0 + j;
        if (r >= M) continue;
        float val = acc[mi][ni][j] + bb;
        if (OUT_HALF) ((_Float16*)Cout)[(size_t)r * N + col] = (_Float16)val;
        else          ((float*)Cout)[(size_t)r * N + col] = val;
      }
    }
  }
}

// ---------------- weight conversion / transpose to fp16 ----------------
__global__ void conv_wcat_k(const float* __restrict__ W_root, const float* __restrict__ W_rel,
                            _Float16* __restrict__ Wt)
{
  int k = blockIdx.x * 256 + threadIdx.x;   // 0..2303
  int n = blockIdx.y;                        // 0..255
  float v = (k < 256) ? W_root[(size_t)k * H1DIM + n]
                      : W_rel[(size_t)(k - 256) * H1DIM + n];
  Wt[(size_t)n * 2304 + k] = (_Float16)v;
}

__global__ void conv_wqkvs_k(const float* __restrict__ Wq, const float* __restrict__ Wk,
                             const float* __restrict__ Wv, const float* __restrict__ Ws,
                             _Float16* __restrict__ Wt)
{
  int k = threadIdx.x;           // 0..255
  int n = blockIdx.y;            // 0..2047
  int sel = n >> 9, c = n & 511;
  const float* W = sel == 0 ? Wq : sel == 1 ? Wk : sel == 2 ? Wv : Ws;
  Wt[(size_t)n * 256 + k] = (_Float16)W[(size_t)k * C2DIM + c];
}

// ---------------- x -> fp16 ----------------
__global__ void conv_xh_k(const float* __restrict__ x, _Float16* __restrict__ xh)
{
  int i = blockIdx.x * blockDim.x + threadIdx.x;
  if (i >= N_NODES * GDIM / 4) return;
  float4 v = ((const float4*)x)[i];
  half4 o = {(_Float16)v.x, (_Float16)v.y, (_Float16)v.z, (_Float16)v.w};
  ((half4*)xh)[i] = o;
}

// ---------------- CSR build ----------------
__global__ void hist_k(const int* __restrict__ dst, const int* __restrict__ et,
                       int* __restrict__ h1c, int* __restrict__ h2c)
{
  int e = blockIdx.x * blockDim.x + threadIdx.x;
  if (e >= N_EDGES) return;
  atomicAdd(&h1c[dst[e]], 1);
  atomicAdd(&h2c[et[e] * N_NODES + dst[e]], 1);
}

__global__ __launch_bounds__(1024) void scan_local_k(
    const int* __restrict__ in, int* __restrict__ out, int* __restrict__ bsum, int n)
{
  __shared__ int s[1024];
  int gi = blockIdx.x * 1024 + threadIdx.x;
  int v = gi < n ? in[gi] : 0;
  s[threadIdx.x] = v; __syncthreads();
  for (int off = 1; off < 1024; off <<= 1) {
    int t = threadIdx.x >= off ? s[threadIdx.x - off] : 0;
    __syncthreads();
    s[threadIdx.x] += t;
    __syncthreads();
  }
  if (gi < n) out[gi] = s[threadIdx.x] - v;
  if (threadIdx.x == 1023) bsum[blockIdx.x] = s[1023];
}

__global__ __launch_bounds__(1024) void scan_small_k(int* __restrict__ bsum, int nb)
{
  __shared__ int s[1024];
  int v = threadIdx.x < nb ? bsum[threadIdx.x] : 0;
  s[threadIdx.x] = v; __syncthreads();
  for (int off = 1; off < 1024; off <<= 1) {
    int t = threadIdx.x >= off ? s[threadIdx.x - off] : 0;
    __syncthreads();
    s[threadIdx.x] += t;
    __syncthreads();
  }
  if (threadIdx.x < nb) bsum[threadIdx.x] = s[threadIdx.x] - v;
}

__global__ void scan_addoff_k(int* __restrict__ out, const int* __restrict__ bsum, int n)
{
  int gi = blockIdx.x * 1024 + threadIdx.x;
  if (gi < n) out[gi] += bsum[blockIdx.x];
}

__global__ void initcur_k(const int* __restrict__ off1, const int* __restrict__ off2,
                          int* __restrict__ cur1, int* __restrict__ cur2)
{
  int i = blockIdx.x * blockDim.x + threadIdx.x;
  if (i < N_NODES) cur1[i] = off1[i];
  if (i < N_NODES * NREL) cur2[i] = off2[i];
  if (i == 0) {
    ((int*)off1)[N_NODES] = N_EDGES;
    ((int*)off2)[N_NODES * NREL] = N_EDGES;
  }
}

__global__ void reorder_k(const int* __restrict__ src, const int* __restrict__ dst,
                          const int* __restrict__ et,
                          int* __restrict__ cur1, int* __restrict__ cur2,
                          int* __restrict__ esrcD, int* __restrict__ esrcRD)
{
  int e = blockIdx.x * blockDim.x + threadIdx.x;
  if (e >= N_EDGES) return;
  int s = src[e], d = dst[e], r = et[e];
  esrcD[atomicAdd(&cur1[d], 1)] = s;
  esrcRD[atomicAdd(&cur2[r * N_NODES + d], 1)] = s;
}

// ---------------- build Xcat = [x | mean_r(x)] in fp16 (gathers fp16 xh) ----------------
__global__ __launch_bounds__(256) void agg_xcat_k(
    const _Float16* __restrict__ xh, const int* __restrict__ off2,
    const int* __restrict__ esrcRD, _Float16* __restrict__ Xcat)
{
  int d = blockIdx.x * 4 + (threadIdx.x >> 6);
  if (d >= N_NODES) return;
  int lane = threadIdx.x & 63;
  _Float16* xrow = Xcat + (size_t)d * 2304;
  // copy own features
  half4 xv = ((const half4*)(xh + (size_t)d * GDIM))[lane];
  *(half4*)(xrow + lane * 4) = xv;
  // per-relation means
  for (int r = 0; r < NREL; ++r) {
    int seg = r * N_NODES + d;
    int beg = off2[seg], end = off2[seg + 1];
    float4 acc = make_float4(0.f, 0.f, 0.f, 0.f);
    for (int e = beg; e < end; ++e) {
      int s = esrcRD[e];
      half4 v = ((const half4*)(xh + (size_t)s * GDIM))[lane];
      acc.x += (float)v.x; acc.y += (float)v.y;
      acc.z += (float)v.z; acc.w += (float)v.w;
    }
    float inv = (end > beg) ? 1.0f / (float)(end - beg) : 0.0f;
    half4 o;
    o.x = (_Float16)(acc.x * inv); o.y = (_Float16)(acc.y * inv);
    o.z = (_Float16)(acc.z * inv); o.w = (_Float16)(acc.w * inv);
    *(half4*)(xrow + 256 + r * 256 + lane * 4) = o;
  }
}

// ---------------- fused attention: fp32 q, fp16 k/v, one-deep prefetch ----------------
__global__ __launch_bounds__(256) void attn_fused_k(
    const float* __restrict__ q, const _Float16* __restrict__ kb,
    const _Float16* __restrict__ vb,
    const int* __restrict__ off1, const int* __restrict__ esrcD,
    float* __restrict__ out)
{
  int d = blockIdx.x * 4 + (threadIdx.x >> 6);
  if (d >= N_NODES) return;
  int lane = threadIdx.x & 63;
  const float4* qrow = (const float4*)(q + (size_t)d * C2DIM);
  float4 q0 = qrow[lane * 2], q1 = qrow[lane * 2 + 1];
  float qf[8] = {q0.x, q0.y, q0.z, q0.w, q1.x, q1.y, q1.z, q1.w};
  float m = -3.4e38f, ssum = 0.f;
  float av[8] = {};
  int beg = off1[d], end = off1[d + 1];
  half8 krN = {}, vrN = {};
  if (beg < end) {
    int s0 = esrcD[beg];
    krN = ((const half8*)(kb + (size_t)s0 * C2DIM))[lane];
    vrN = ((const half8*)(vb + (size_t)s0 * C2DIM))[lane];
  }
  for (int e = beg; e < end; ++e) {
    half8 kr = krN, vr = vrN;
    if (e + 1 < end) {                       // prefetch next edge's rows
      int s1 = esrcD[e + 1];
      krN = ((const half8*)(kb + (size_t)s1 * C2DIM))[lane];
      vrN = ((const half8*)(vb + (size_t)s1 * C2DIM))[lane];
    }
    float p = 0.f;
#pragma unroll
    for (int j = 0; j < 8; ++j) p += qf[j] * (float)kr[j];
    p += __shfl_xor(p, 1); p += __shfl_xor(p, 2);
    p += __shfl_xor(p, 4); p += __shfl_xor(p, 8);
    float a = p * 0.08838834764831845f;      // 1/sqrt(128)
    float mn = fmaxf(m, a);
    float corr = __expf(m - mn), w = __expf(a - mn);
    ssum = ssum * corr + w;
#pragma unroll
    for (int j = 0; j < 8; ++j) av[j] = av[j] * corr + w * (float)vr[j];
    m = mn;
  }
  float inv = 1.0f / fmaxf(ssum, 1e-16f);
  float* orow = out + (size_t)d * C2DIM + lane * 8;
#pragma unroll
  for (int j = 0; j < 8; ++j) orow[j] += av[j] * inv;
}

// ---------------- BN ----------------
__global__ __launch_bounds__(512) void bn_stats_k(
    const float* __restrict__ x, float* __restrict__ sums, float* __restrict__ sumsq)
{
  int c = threadIdx.x;
  float s = 0.f, sq = 0.f;
  for (int row = blockIdx.x; row < N_NODES; row += gridDim.x) {
    float v = x[(size_t)row * C2DIM + c];
    s += v; sq += v * v;
  }
  atomicAdd(&sums[c], s);
  atomicAdd(&sumsq[c], sq);
}

__global__ void bn_final_k(const float* __restrict__ sums, const float* __restrict__ sumsq,
                           const float* __restrict__ gamma, const float* __restrict__ beta,
                           float* __restrict__ scale, float* __restrict__ shift)
{
  int c = threadIdx.x;
  float mu  = sums[c] * (1.0f / N_NODES);
  float var = sumsq[c] * (1.0f / N_NODES) - mu * mu;
  float sc  = gamma[c] * rsqrtf(var + 1e-5f);
  scale[c] = sc;
  shift[c] = beta[c] - mu * sc;
}

__global__ void bn_apply_k(float* __restrict__ x, const float* __restrict__ scale,
                           const float* __restrict__ shift, int total)
{
  int i = blockIdx.x * blockDim.x + threadIdx.x;
  if (i >= total) return;
  int c = i & (C2DIM - 1);
  float v = x[i] * scale[c] + shift[c];
  x[i] = v >= 0.f ? v : 0.01f * v;
}

// ---------------- launch ----------------
extern "C" void kernel_launch(void* const* d_in, const int* in_sizes, int n_in,
                              void* d_out, int out_size, void* d_ws, size_t ws_size,
                              hipStream_t stream)
{
  const float* x      = (const float*)d_in[0];
  const int*   ei     = (const int*)d_in[2];
  const int*   src    = ei;
  const int*   dst    = ei + N_EDGES;
  const int*   etype  = (const int*)d_in[3];
  const float* W_rel  = (const float*)d_in[4];
  const float* W_root = (const float*)d_in[5];
  const float* b_rgcn = (const float*)d_in[6];
  const float* W_q = (const float*)d_in[7];  const float* b_q = (const float*)d_in[8];
  const float* W_k = (const float*)d_in[9];  const float* b_k = (const float*)d_in[10];
  const float* W_v = (const float*)d_in[11]; const float* b_v = (const float*)d_in[12];
  const float* W_s = (const float*)d_in[13]; const float* b_s = (const float*)d_in[14];
  const float* gamma = (const float*)d_in[15];
  const float* beta  = (const float*)d_in[16];
  float* out = (float*)d_out;

  // ---- workspace layout (total 108,640,544 <= proven-safe budget) ----
  char* ws = (char*)d_ws;
  _Float16* Xcat   = (_Float16*)(ws + 0);          // N x 2304 fp16 = 92,160,000
  float*    qbuf   = (float*)(ws + 0);             // reuse: q fp32 (40.96 MB)
  _Float16* kbuf   = (_Float16*)(ws + 40960000);   // reuse: k fp16 (20.48 MB)
  _Float16* vbuf   = (_Float16*)(ws + 61440000);   // reuse: v fp16 (20.48 MB)
  _Float16* Wt_cat = (_Float16*)(ws + 92160000);   // 256 x 2304 fp16 = 1,179,648
  _Float16* Wt_qk  = (_Float16*)(ws + 93339648);   // 2048 x 256 fp16 = 1,048,576
  _Float16* h1h    = (_Float16*)(ws + 94388224);   // N x 256 fp16 = 10,240,000
  _Float16* xh     = h1h;                          // xh aliases h1h (dead before h1 GEMM)

  char* C = ws + 104628224;                  // CSR area
  int* cur1   = (int*)(C + 0);               // 80,000   (hist1, then cursor)
  int* cur2   = (int*)(C + 80000);           // 640,000  (hist2, then cursor)
  int* off1   = (int*)(C + 720000);          // 80,016
  int* off2   = (int*)(C + 800016);          // 640,016
  int* esrcD  = (int*)(C + 1440032);         // 1,280,000
  int* esrcRD = (int*)(C + 2720032);         // 1,280,000
  int* bsum   = (int*)(C + 4000032);         // 4,096
  float* bns  = (float*)(C + 4004128);       // 8,192
  float* bnsum = bns, *bnsq = bns + 512, *bnscale = bns + 1024, *bnshift = bns + 1536;

  hipMemsetAsync(C, 0, 720000, stream);      // hist1 + hist2
  hipMemsetAsync(bns, 0, 8192, stream);

  dim3 blk(256);
  const int NB1 = (N_NODES + 1023) / 1024;          // 20
  const int NB2 = (N_NODES * NREL + 1023) / 1024;   // 157

  // ---- CSR build ----
  hist_k<<<dim3((N_EDGES + 255) / 256), blk, 0, stream>>>(dst, etype, cur1, cur2);
  scan_local_k<<<dim3(NB1), dim3(1024), 0, stream>>>(cur1, off1, bsum, N_NODES);
  scan_small_k<<<dim3(1), dim3(1024), 0, stream>>>(bsum, NB1);
  scan_addoff_k<<<dim3(NB1), dim3(1024), 0, stream>>>(off1, bsum, N_NODES);
  scan_local_k<<<dim3(NB2), dim3(1024), 0, stream>>>(cur2, off2, bsum, N_NODES * NREL);
  scan_small_k<<<dim3(1), dim3(1024), 0, stream>>>(bsum, NB2);
  scan_addoff_k<<<dim3(NB2), dim3(1024), 0, stream>>>(off2, bsum, N_NODES * NREL);
  initcur_k<<<dim3((N_NODES * NREL + 255) / 256), blk, 0, stream>>>(off1, off2, cur1, cur2);
  reorder_k<<<dim3((N_EDGES + 255) / 256), blk, 0, stream>>>(
      src, dst, etype, cur1, cur2, esrcD, esrcRD);

  // ---- conversions (fp16) ----
  conv_wcat_k<<<dim3(9, 256), blk, 0, stream>>>(W_root, W_rel, Wt_cat);
  conv_wqkvs_k<<<dim3(1, 2048), blk, 0, stream>>>(W_q, W_k, W_v, W_s, Wt_qk);
  conv_xh_k<<<dim3((N_NODES * GDIM / 4 + 255) / 256), blk, 0, stream>>>(x, xh);

  // ---- Xcat = [x | mean_r(x)] (fp16 gathers) ----
  agg_xcat_k<<<dim3((N_NODES + 3) / 4), blk, 0, stream>>>(xh, off2, esrcRD, Xcat);

  // ---- h1 (fp16) = Xcat @ Wcat + b_rgcn : one K=2304 GEMM (overwrites xh) ----
  gemm_mfma_k<1><<<dim3(H1DIM / 128, (N_NODES + 127) / 128), blk, 0, stream>>>(
      Xcat, Wt_cat, b_rgcn, h1h, N_NODES, H1DIM, 2304);

  // ---- q (fp32), k (fp16), v (fp16), skip (fp32 -> d_out) ----
  gemm_mfma_k<0><<<dim3(C2DIM / 128, (N_NODES + 127) / 128), blk, 0, stream>>>(
      h1h, Wt_qk + 0 * 512 * 256, b_q, qbuf, N_NODES, C2DIM, H1DIM);
  gemm_mfma_k<1><<<dim3(C2DIM / 128, (N_NODES + 127) / 128), blk, 0, stream>>>(
      h1h, Wt_qk + 1 * 512 * 256, b_k, kbuf, N_NODES, C2DIM, H1DIM);
  gemm_mfma_k<1><<<dim3(C2DIM / 128, (N_NODES + 127) / 128), blk, 0, stream>>>(
      h1h, Wt_qk + 2 * 512 * 256, b_v, vbuf, N_NODES, C2DIM, H1DIM);
  gemm_mfma_k<0><<<dim3(C2DIM / 128, (N_NODES + 127) / 128), blk, 0, stream>>>(
      h1h, Wt_qk + 3 * 512 * 256, b_s, out, N_NODES, C2DIM, H1DIM);

  // ---- fused attention adds into d_out (on top of skip) ----
  attn_fused_k<<<dim3((N_NODES + 3) / 4), blk, 0, stream>>>(
      qbuf, kbuf, vbuf, off1, esrcD, out);

  // ---- BatchNorm + LeakyReLU (in place on d_out) ----
  bn_stats_k<<<dim3(208), dim3(512), 0, stream>>>(out, bnsum, bnsq);
  bn_final_k<<<dim3(1), dim3(512), 0, stream>>>(bnsum, bnsq, gamma, beta, bnscale, bnshift);
  bn_apply_k<<<dim3((N_NODES * C2DIM + 255) / 256), blk, 0, stream>>>(
      out, bnscale, bnshift, N_NODES * C2DIM);
}

// Round 6
// 391.386 us; speedup vs baseline: 16.9677x; 1.1295x over previous
//
#include <hip/hip_runtime.h>

// ---------------- problem constants ----------------
static const int N_NODES = 20000;
static const int N_EDGES = 320000;
static const int GDIM    = 256;   // input feature dim
static const int H1DIM   = 256;   // RGCN output dim
static const int C2DIM   = 512;   // HEADS * H2
static const int NREL    = 8;
static const int NSEG    = N_NODES * NREL;   // 160000

typedef _Float16 __attribute__((ext_vector_type(8))) half8;
typedef _Float16 __attribute__((ext_vector_type(4))) half4;
typedef __attribute__((ext_vector_type(4))) float f32x4;

__device__ __forceinline__ void gload_lds16(const void* g, void* l) {
  __builtin_amdgcn_global_load_lds(
      (const __attribute__((address_space(1))) unsigned int*)g,
      (__attribute__((address_space(3))) unsigned int*)l, 16, 0, 0);
}

// bijective XCD-chunked block swizzle (m204): consecutive wgid -> same XCD
__device__ __forceinline__ void swz_bxy(int& bx, int& by) {
  int nx   = gridDim.x;
  int nwg  = nx * gridDim.y;
  int orig = blockIdx.y * nx + blockIdx.x;
  int xcd  = orig & 7;
  int q    = nwg >> 3, r = nwg & 7;
  int base = xcd < r ? xcd * (q + 1) : r * (q + 1) + (xcd - r) * q;
  int wgid = base + (orig >> 3);
  bx = wgid % nx; by = wgid / nx;
}

// ---------------- fp16 MFMA GEMM core macro-ish: 128x128 tile, BK=64 ----------------
// Staging: global_load_lds dwordx4, LINEAR LDS dest + pre-swizzled global source
// (chunk c ^= row&7); reads use the same XOR (rule-21 involution).
// Boundary rows read in-workspace garbage; masked epilogue discards them.

template<int OUT_HALF>
__global__ __launch_bounds__(256) void gemm_mfma_k(
    const _Float16* __restrict__ A, const _Float16* __restrict__ Bt,
    const float* __restrict__ bias, void* __restrict__ Cout,
    int M, int N, int K)
{
  __shared__ _Float16 As[128 * 64];
  __shared__ _Float16 Bs[128 * 64];
  int bx, by; swz_bxy(bx, by);
  const int tid  = threadIdx.x;
  const int wid  = tid >> 6, lane = tid & 63;
  const int wr   = wid >> 1, wc = wid & 1;
  const int brow = by * 128;
  const int bcol = bx * 128;
  const int l15  = lane & 15, lhi = lane >> 4;
  const int srow = wid * 32;
  const int lrow = lane >> 3;
  const int lchk = lane & 7;

  f32x4 acc[4][4] = {};

  for (int k0 = 0; k0 < K; k0 += 64) {
    __syncthreads();
#pragma unroll
    for (int i = 0; i < 4; ++i) {
      int row = srow + i * 8 + lrow;
      int gc  = lchk ^ (row & 7);
      gload_lds16(A  + (size_t)(brow + row) * K + k0 + gc * 8,
                  &As[(srow + i * 8) * 64]);
      gload_lds16(Bt + (size_t)(bcol + row) * K + k0 + gc * 8,
                  &Bs[(srow + i * 8) * 64]);
    }
    __syncthreads();
#pragma unroll
    for (int kf = 0; kf < 2; ++kf) {
      int cc = kf * 4 + lhi;
      half8 af[4], bfr[4];
#pragma unroll
      for (int mi = 0; mi < 4; ++mi) {
        int row = wr * 64 + mi * 16 + l15;
        af[mi] = ((const half8*)As)[row * 8 + (cc ^ (row & 7))];
      }
#pragma unroll
      for (int ni = 0; ni < 4; ++ni) {
        int row = wc * 64 + ni * 16 + l15;
        bfr[ni] = ((const half8*)Bs)[row * 8 + (cc ^ (row & 7))];
      }
#pragma unroll
      for (int mi = 0; mi < 4; ++mi)
#pragma unroll
        for (int ni = 0; ni < 4; ++ni)
          acc[mi][ni] = __builtin_amdgcn_mfma_f32_16x16x32_f16(
              af[mi], bfr[ni], acc[mi][ni], 0, 0, 0);
    }
  }
#pragma unroll
  for (int ni = 0; ni < 4; ++ni) {
    int col = bcol + wc * 64 + ni * 16 + l15;
    float bb = bias ? bias[col] : 0.f;
#pragma unroll
    for (int mi = 0; mi < 4; ++mi) {
      int row0 = brow + wr * 64 + mi * 16 + lhi * 4;
#pragma unroll
      for (int j = 0; j < 4; ++j) {
        int r = row0 + j;
        if (r >= M) continue;
        float val = acc[mi][ni][j] + bb;
        if (OUT_HALF) ((_Float16*)Cout)[(size_t)r * N + col] = (_Float16)val;
        else          ((float*)Cout)[(size_t)r * N + col] = val;
      }
    }
  }
}

// ---- fused q/k/v/skip GEMM: A(Mx256) @ Wt(2048x256)^T, mixed-dtype epilogue ----
__global__ __launch_bounds__(256) void gemm_qkvs_k(
    const _Float16* __restrict__ A, const _Float16* __restrict__ Bt,
    const float* __restrict__ bias_cat,
    float* __restrict__ qbuf, _Float16* __restrict__ kbuf,
    _Float16* __restrict__ vbuf, float* __restrict__ outp, int M)
{
  const int K = 256, N = 2048;
  __shared__ _Float16 As[128 * 64];
  __shared__ _Float16 Bs[128 * 64];
  int bx, by; swz_bxy(bx, by);
  const int tid  = threadIdx.x;
  const int wid  = tid >> 6, lane = tid & 63;
  const int wr   = wid >> 1, wc = wid & 1;
  const int brow = by * 128;
  const int bcol = bx * 128;
  const int l15  = lane & 15, lhi = lane >> 4;
  const int srow = wid * 32;
  const int lrow = lane >> 3;
  const int lchk = lane & 7;

  f32x4 acc[4][4] = {};

  for (int k0 = 0; k0 < K; k0 += 64) {
    __syncthreads();
#pragma unroll
    for (int i = 0; i < 4; ++i) {
      int row = srow + i * 8 + lrow;
      int gc  = lchk ^ (row & 7);
      gload_lds16(A  + (size_t)(brow + row) * K + k0 + gc * 8,
                  &As[(srow + i * 8) * 64]);
      gload_lds16(Bt + (size_t)(bcol + row) * K + k0 + gc * 8,
                  &Bs[(srow + i * 8) * 64]);
    }
    __syncthreads();
#pragma unroll
    for (int kf = 0; kf < 2; ++kf) {
      int cc = kf * 4 + lhi;
      half8 af[4], bfr[4];
#pragma unroll
      for (int mi = 0; mi < 4; ++mi) {
        int row = wr * 64 + mi * 16 + l15;
        af[mi] = ((const half8*)As)[row * 8 + (cc ^ (row & 7))];
      }
#pragma unroll
      for (int ni = 0; ni < 4; ++ni) {
        int row = wc * 64 + ni * 16 + l15;
        bfr[ni] = ((const half8*)Bs)[row * 8 + (cc ^ (row & 7))];
      }
#pragma unroll
      for (int mi = 0; mi < 4; ++mi)
#pragma unroll
        for (int ni = 0; ni < 4; ++ni)
          acc[mi][ni] = __builtin_amdgcn_mfma_f32_16x16x32_f16(
              af[mi], bfr[ni], acc[mi][ni], 0, 0, 0);
    }
  }
#pragma unroll
  for (int ni = 0; ni < 4; ++ni) {
    int colbase = bcol + wc * 64 + ni * 16;     // 16-aligned -> sel wave-uniform
    int sel = colbase >> 9;
    int c   = (colbase & 511) + l15;
    float bb = bias_cat[colbase + l15];
#pragma unroll
    for (int mi = 0; mi < 4; ++mi) {
      int row0 = brow + wr * 64 + mi * 16 + lhi * 4;
#pragma unroll
      for (int j = 0; j < 4; ++j) {
        int r = row0 + j;
        if (r >= M) continue;
        float val = acc[mi][ni][j] + bb;
        if      (sel == 0) qbuf[(size_t)r * 512 + c] = val;
        else if (sel == 1) kbuf[(size_t)r * 512 + c] = (_Float16)val;
        else if (sel == 2) vbuf[(size_t)r * 512 + c] = (_Float16)val;
        else               outp[(size_t)r * 512 + c] = val;
      }
    }
  }
}

// ---------------- weight conversion / transpose to fp16 ----------------
__global__ void conv_wcat_k(const float* __restrict__ W_root, const float* __restrict__ W_rel,
                            _Float16* __restrict__ Wt)
{
  int k = blockIdx.x * 256 + threadIdx.x;   // 0..2303
  int n = blockIdx.y;                        // 0..255
  float v = (k < 256) ? W_root[(size_t)k * H1DIM + n]
                      : W_rel[(size_t)(k - 256) * H1DIM + n];
  Wt[(size_t)n * 2304 + k] = (_Float16)v;
}

__global__ void conv_wqkvs_k(const float* __restrict__ Wq, const float* __restrict__ Wk,
                             const float* __restrict__ Wv, const float* __restrict__ Ws,
                             const float* __restrict__ bq, const float* __restrict__ bk,
                             const float* __restrict__ bv, const float* __restrict__ bs,
                             _Float16* __restrict__ Wt, float* __restrict__ bias_cat)
{
  int k = threadIdx.x;           // 0..255
  int n = blockIdx.y;            // 0..2047
  int sel = n >> 9, c = n & 511;
  const float* W = sel == 0 ? Wq : sel == 1 ? Wk : sel == 2 ? Wv : Ws;
  Wt[(size_t)n * 256 + k] = (_Float16)W[(size_t)k * C2DIM + c];
  if (k == 0) {
    const float* B = sel == 0 ? bq : sel == 1 ? bk : sel == 2 ? bv : bs;
    bias_cat[n] = B[c];
  }
}

__global__ void conv_xh_k(const float* __restrict__ x, _Float16* __restrict__ xh)
{
  int i = blockIdx.x * blockDim.x + threadIdx.x;
  if (i >= N_NODES * GDIM / 4) return;
  float4 v = ((const float4*)x)[i];
  half4 o = {(_Float16)v.x, (_Float16)v.y, (_Float16)v.z, (_Float16)v.w};
  ((half4*)xh)[i] = o;
}

// ---------------- single CSR keyed by seg = dst*8 + rel ----------------
__global__ void hist_k(const int* __restrict__ dst, const int* __restrict__ et,
                       int* __restrict__ h)
{
  int e = blockIdx.x * blockDim.x + threadIdx.x;
  if (e >= N_EDGES) return;
  atomicAdd(&h[dst[e] * NREL + et[e]], 1);
}

__global__ __launch_bounds__(1024) void scan_local_k(
    const int* __restrict__ in, int* __restrict__ out, int* __restrict__ bsum, int n)
{
  __shared__ int s[1024];
  int gi = blockIdx.x * 1024 + threadIdx.x;
  int v = gi < n ? in[gi] : 0;
  s[threadIdx.x] = v; __syncthreads();
  for (int off = 1; off < 1024; off <<= 1) {
    int t = threadIdx.x >= off ? s[threadIdx.x - off] : 0;
    __syncthreads();
    s[threadIdx.x] += t;
    __syncthreads();
  }
  if (gi < n) out[gi] = s[threadIdx.x] - v;
  if (threadIdx.x == 1023) bsum[blockIdx.x] = s[1023];
}

__global__ __launch_bounds__(1024) void scan_small_k(int* __restrict__ bsum, int nb)
{
  __shared__ int s[1024];
  int v = threadIdx.x < nb ? bsum[threadIdx.x] : 0;
  s[threadIdx.x] = v; __syncthreads();
  for (int off = 1; off < 1024; off <<= 1) {
    int t = threadIdx.x >= off ? s[threadIdx.x - off] : 0;
    __syncthreads();
    s[threadIdx.x] += t;
    __syncthreads();
  }
  if (threadIdx.x < nb) bsum[threadIdx.x] = s[threadIdx.x] - v;
}

__global__ void scan_addoff_k(int* __restrict__ out, const int* __restrict__ bsum, int n)
{
  int gi = blockIdx.x * 1024 + threadIdx.x;
  if (gi < n) out[gi] += bsum[blockIdx.x];
}

__global__ void initcur_k(int* __restrict__ off, int* __restrict__ cur)
{
  int i = blockIdx.x * blockDim.x + threadIdx.x;
  if (i < NSEG) cur[i] = off[i];
  if (i == 0) off[NSEG] = N_EDGES;
}

__global__ void reorder_k(const int* __restrict__ src, const int* __restrict__ dst,
                          const int* __restrict__ et,
                          int* __restrict__ cur, int* __restrict__ esrc)
{
  int e = blockIdx.x * blockDim.x + threadIdx.x;
  if (e >= N_EDGES) return;
  int s = src[e];
  int seg = dst[e] * NREL + et[e];
  esrc[atomicAdd(&cur[seg], 1)] = s;
}

// ---------------- build Xcat = [x | mean_r(x)] in fp16 ----------------
__global__ __launch_bounds__(256) void agg_xcat_k(
    const _Float16* __restrict__ xh, const int* __restrict__ off,
    const int* __restrict__ esrc, _Float16* __restrict__ Xcat)
{
  int d = blockIdx.x * 4 + (threadIdx.x >> 6);
  if (d >= N_NODES) return;
  int lane = threadIdx.x & 63;
  _Float16* xrow = Xcat + (size_t)d * 2304;
  half4 xv = ((const half4*)(xh + (size_t)d * GDIM))[lane];
  *(half4*)(xrow + lane * 4) = xv;
  for (int r = 0; r < NREL; ++r) {
    int seg = d * NREL + r;
    int beg = off[seg], end = off[seg + 1];
    float4 acc = make_float4(0.f, 0.f, 0.f, 0.f);
    for (int e = beg; e < end; ++e) {
      int s = esrc[e];
      half4 v = ((const half4*)(xh + (size_t)s * GDIM))[lane];
      acc.x += (float)v.x; acc.y += (float)v.y;
      acc.z += (float)v.z; acc.w += (float)v.w;
    }
    float inv = (end > beg) ? 1.0f / (float)(end - beg) : 0.0f;
    half4 o;
    o.x = (_Float16)(acc.x * inv); o.y = (_Float16)(acc.y * inv);
    o.z = (_Float16)(acc.z * inv); o.w = (_Float16)(acc.w * inv);
    *(half4*)(xrow + 256 + r * 256 + lane * 4) = o;
  }
}

// ---------------- fused attention: fp32 q, fp16 k/v, one-deep prefetch ----------------
__global__ __launch_bounds__(256) void attn_fused_k(
    const float* __restrict__ q, const _Float16* __restrict__ kb,
    const _Float16* __restrict__ vb,
    const int* __restrict__ off, const int* __restrict__ esrc,
    float* __restrict__ out)
{
  int d = blockIdx.x * 4 + (threadIdx.x >> 6);
  if (d >= N_NODES) return;
  int lane = threadIdx.x & 63;
  const float4* qrow = (const float4*)(q + (size_t)d * C2DIM);
  float4 q0 = qrow[lane * 2], q1 = qrow[lane * 2 + 1];
  float qf[8] = {q0.x, q0.y, q0.z, q0.w, q1.x, q1.y, q1.z, q1.w};
  float m = -3.4e38f, ssum = 0.f;
  float av[8] = {};
  int beg = off[d * NREL], end = off[d * NREL + NREL];
  half8 krN = {}, vrN = {};
  if (beg < end) {
    int s0 = esrc[beg];
    krN = ((const half8*)(kb + (size_t)s0 * C2DIM))[lane];
    vrN = ((const half8*)(vb + (size_t)s0 * C2DIM))[lane];
  }
  for (int e = beg; e < end; ++e) {
    half8 kr = krN, vr = vrN;
    if (e + 1 < end) {
      int s1 = esrc[e + 1];
      krN = ((const half8*)(kb + (size_t)s1 * C2DIM))[lane];
      vrN = ((const half8*)(vb + (size_t)s1 * C2DIM))[lane];
    }
    float p = 0.f;
#pragma unroll
    for (int j = 0; j < 8; ++j) p += qf[j] * (float)kr[j];
    p += __shfl_xor(p, 1); p += __shfl_xor(p, 2);
    p += __shfl_xor(p, 4); p += __shfl_xor(p, 8);
    float a = p * 0.08838834764831845f;      // 1/sqrt(128)
    float mn = fmaxf(m, a);
    float corr = __expf(m - mn), w = __expf(a - mn);
    ssum = ssum * corr + w;
#pragma unroll
    for (int j = 0; j < 8; ++j) av[j] = av[j] * corr + w * (float)vr[j];
    m = mn;
  }
  float inv = 1.0f / fmaxf(ssum, 1e-16f);
  float* orow = out + (size_t)d * C2DIM + lane * 8;
#pragma unroll
  for (int j = 0; j < 8; ++j) orow[j] += av[j] * inv;
}

// ---------------- BN ----------------
__global__ __launch_bounds__(512) void bn_stats_k(
    const float* __restrict__ x, float* __restrict__ sums, float* __restrict__ sumsq)
{
  int c = threadIdx.x;
  float s = 0.f, sq = 0.f;
  for (int row = blockIdx.x; row < N_NODES; row += gridDim.x) {
    float v = x[(size_t)row * C2DIM + c];
    s += v; sq += v * v;
  }
  atomicAdd(&sums[c], s);
  atomicAdd(&sumsq[c], sq);
}

__global__ void bn_final_k(const float* __restrict__ sums, const float* __restrict__ sumsq,
                           const float* __restrict__ gamma, const float* __restrict__ beta,
                           float* __restrict__ scale, float* __restrict__ shift)
{
  int c = threadIdx.x;
  float mu  = sums[c] * (1.0f / N_NODES);
  float var = sumsq[c] * (1.0f / N_NODES) - mu * mu;
  float sc  = gamma[c] * rsqrtf(var + 1e-5f);
  scale[c] = sc;
  shift[c] = beta[c] - mu * sc;
}

__global__ void bn_apply_k(float* __restrict__ x, const float* __restrict__ scale,
                           const float* __restrict__ shift, int total)
{
  int i = blockIdx.x * blockDim.x + threadIdx.x;
  if (i >= total) return;
  int c = i & (C2DIM - 1);
  float v = x[i] * scale[c] + shift[c];
  x[i] = v >= 0.f ? v : 0.01f * v;
}

// ---------------- launch ----------------
extern "C" void kernel_launch(void* const* d_in, const int* in_sizes, int n_in,
                              void* d_out, int out_size, void* d_ws, size_t ws_size,
                              hipStream_t stream)
{
  const float* x      = (const float*)d_in[0];
  const int*   ei     = (const int*)d_in[2];
  const int*   src    = ei;
  const int*   dst    = ei + N_EDGES;
  const int*   etype  = (const int*)d_in[3];
  const float* W_rel  = (const float*)d_in[4];
  const float* W_root = (const float*)d_in[5];
  const float* b_rgcn = (const float*)d_in[6];
  const float* W_q = (const float*)d_in[7];  const float* b_q = (const float*)d_in[8];
  const float* W_k = (const float*)d_in[9];  const float* b_k = (const float*)d_in[10];
  const float* W_v = (const float*)d_in[11]; const float* b_v = (const float*)d_in[12];
  const float* W_s = (const float*)d_in[13]; const float* b_s = (const float*)d_in[14];
  const float* gamma = (const float*)d_in[15];
  const float* beta  = (const float*)d_in[16];
  float* out = (float*)d_out;

  // ---- workspace layout ----
  char* ws = (char*)d_ws;
  _Float16* Xcat   = (_Float16*)(ws + 0);          // N x 2304 fp16 = 92,160,000
  float*    qbuf   = (float*)(ws + 0);             // reuse after Xcat dead (40.96 MB)
  _Float16* kbuf   = (_Float16*)(ws + 40960000);   // k fp16 (20.48 MB)
  _Float16* vbuf   = (_Float16*)(ws + 61440000);   // v fp16 (20.48 MB)
  _Float16* Wt_cat = (_Float16*)(ws + 92160000);   // 256 x 2304 fp16 = 1,179,648
  _Float16* Wt_qk  = (_Float16*)(ws + 93339648);   // 2048 x 256 fp16 = 1,048,576
  _Float16* h1h    = (_Float16*)(ws + 94388224);   // N x 256 fp16 = 10,240,000
  _Float16* xh     = h1h;                          // xh aliases h1h (dead before h1 GEMM)

  char* C = ws + 104628224;                  // CSR area (ends < 107.3 MB)
  int*   cur      = (int*)(C + 0);           // 640,000  (hist, then cursor)
  int*   off      = (int*)(C + 640000);      // 640,016  (160001 ints)
  int*   esrc     = (int*)(C + 1280016);     // 1,280,000
  int*   bsum     = (int*)(C + 2560016);     // 4,096
  float* bns      = (float*)(C + 2564112);   // 8,192
  float* bias_cat = (float*)(C + 2572304);   // 8,192
  float* bnsum = bns, *bnsq = bns + 512, *bnscale = bns + 1024, *bnshift = bns + 1536;

  hipMemsetAsync(C, 0, 640000, stream);      // hist
  hipMemsetAsync(bns, 0, 8192, stream);

  dim3 blk(256);
  const int NB = (NSEG + 1023) / 1024;       // 157

  // ---- CSR build (single, keyed by dst*8+rel) ----
  hist_k<<<dim3((N_EDGES + 255) / 256), blk, 0, stream>>>(dst, etype, cur);
  scan_local_k<<<dim3(NB), dim3(1024), 0, stream>>>(cur, off, bsum, NSEG);
  scan_small_k<<<dim3(1), dim3(1024), 0, stream>>>(bsum, NB);
  scan_addoff_k<<<dim3(NB), dim3(1024), 0, stream>>>(off, bsum, NSEG);
  initcur_k<<<dim3((NSEG + 255) / 256), blk, 0, stream>>>(off, cur);
  reorder_k<<<dim3((N_EDGES + 255) / 256), blk, 0, stream>>>(
      src, dst, etype, cur, esrc);

  // ---- conversions (fp16) ----
  conv_wcat_k<<<dim3(9, 256), blk, 0, stream>>>(W_root, W_rel, Wt_cat);
  conv_wqkvs_k<<<dim3(1, 2048), blk, 0, stream>>>(
      W_q, W_k, W_v, W_s, b_q, b_k, b_v, b_s, Wt_qk, bias_cat);
  conv_xh_k<<<dim3((N_NODES * GDIM / 4 + 255) / 256), blk, 0, stream>>>(x, xh);

  // ---- Xcat = [x | mean_r(x)] ----
  agg_xcat_k<<<dim3((N_NODES + 3) / 4), blk, 0, stream>>>(xh, off, esrc, Xcat);

  // ---- h1 (fp16) = Xcat @ Wcat + b_rgcn : one K=2304 GEMM ----
  gemm_mfma_k<1><<<dim3(H1DIM / 128, (N_NODES + 127) / 128), blk, 0, stream>>>(
      Xcat, Wt_cat, b_rgcn, h1h, N_NODES, H1DIM, 2304);

  // ---- fused q/k/v/skip GEMM (N=2048, mixed epilogue) ----
  gemm_qkvs_k<<<dim3(2048 / 128, (N_NODES + 127) / 128), blk, 0, stream>>>(
      h1h, Wt_qk, bias_cat, qbuf, kbuf, vbuf, out, N_NODES);

  // ---- fused attention adds into d_out (on top of skip) ----
  attn_fused_k<<<dim3((N_NODES + 3) / 4), blk, 0, stream>>>(
      qbuf, kbuf, vbuf, off, esrc, out);

  // ---- BatchNorm + LeakyReLU (in place on d_out) ----
  bn_stats_k<<<dim3(208), dim3(512), 0, stream>>>(out, bnsum, bnsq);
  bn_final_k<<<dim3(1), dim3(512), 0, stream>>>(bnsum, bnsq, gamma, beta, bnscale, bnshift);
  bn_apply_k<<<dim3((N_NODES * C2DIM + 255) / 256), blk, 0, stream>>>(
      out, bnscale, bnshift, N_NODES * C2DIM);
}

// Round 7
// 357.554 us; speedup vs baseline: 18.5732x; 1.0946x over previous
//
#include <hip/hip_runtime.h>

// ---------------- problem constants ----------------
static const int N_NODES = 20000;
static const int N_EDGES = 320000;
static const int GDIM    = 256;   // input feature dim
static const int H1DIM   = 256;   // RGCN output dim
static const int C2DIM   = 512;   // HEADS * H2
static const int NREL    = 8;
static const int NSEG    = N_NODES * NREL;   // 160000

typedef _Float16 __attribute__((ext_vector_type(8))) half8;
typedef _Float16 __attribute__((ext_vector_type(4))) half4;
typedef __attribute__((ext_vector_type(4))) float f32x4;

__device__ __forceinline__ void gload_lds16(const void* g, void* l) {
  __builtin_amdgcn_global_load_lds(
      (const __attribute__((address_space(1))) unsigned int*)g,
      (__attribute__((address_space(3))) unsigned int*)l, 16, 0, 0);
}

// bijective XCD-chunked block swizzle (m204)
__device__ __forceinline__ void swz_bxy(int& bx, int& by) {
  int nx   = gridDim.x;
  int nwg  = nx * gridDim.y;
  int orig = blockIdx.y * nx + blockIdx.x;
  int xcd  = orig & 7;
  int q    = nwg >> 3, r = nwg & 7;
  int base = xcd < r ? xcd * (q + 1) : r * (q + 1) + (xcd - r) * q;
  int wgid = base + (orig >> 3);
  bx = wgid % nx; by = wgid / nx;
}

// ---------------- fp16 MFMA GEMM: C = A(MxK) @ Bt(NxK)^T + bias ----------------
// 128x128 tile, 4 waves (2x2), BK=64. global_load_lds dwordx4 staging with
// linear LDS dest + pre-swizzled global source (rule-21 involution c ^= row&7).
template<int OUT_HALF>
__global__ __launch_bounds__(256) void gemm_mfma_k(
    const _Float16* __restrict__ A, const _Float16* __restrict__ Bt,
    const float* __restrict__ bias, void* __restrict__ Cout,
    int M, int N, int K)
{
  __shared__ _Float16 As[128 * 64];
  __shared__ _Float16 Bs[128 * 64];
  int bx, by; swz_bxy(bx, by);
  const int tid  = threadIdx.x;
  const int wid  = tid >> 6, lane = tid & 63;
  const int wr   = wid >> 1, wc = wid & 1;
  const int brow = by * 128;
  const int bcol = bx * 128;
  const int l15  = lane & 15, lhi = lane >> 4;
  const int srow = wid * 32;
  const int lrow = lane >> 3;
  const int lchk = lane & 7;

  f32x4 acc[4][4] = {};

  for (int k0 = 0; k0 < K; k0 += 64) {
    __syncthreads();
#pragma unroll
    for (int i = 0; i < 4; ++i) {
      int row = srow + i * 8 + lrow;
      int gc  = lchk ^ (row & 7);
      gload_lds16(A  + (size_t)(brow + row) * K + k0 + gc * 8,
                  &As[(srow + i * 8) * 64]);
      gload_lds16(Bt + (size_t)(bcol + row) * K + k0 + gc * 8,
                  &Bs[(srow + i * 8) * 64]);
    }
    __syncthreads();
#pragma unroll
    for (int kf = 0; kf < 2; ++kf) {
      int cc = kf * 4 + lhi;
      half8 af[4], bfr[4];
#pragma unroll
      for (int mi = 0; mi < 4; ++mi) {
        int row = wr * 64 + mi * 16 + l15;
        af[mi] = ((const half8*)As)[row * 8 + (cc ^ (row & 7))];
      }
#pragma unroll
      for (int ni = 0; ni < 4; ++ni) {
        int row = wc * 64 + ni * 16 + l15;
        bfr[ni] = ((const half8*)Bs)[row * 8 + (cc ^ (row & 7))];
      }
#pragma unroll
      for (int mi = 0; mi < 4; ++mi)
#pragma unroll
        for (int ni = 0; ni < 4; ++ni)
          acc[mi][ni] = __builtin_amdgcn_mfma_f32_16x16x32_f16(
              af[mi], bfr[ni], acc[mi][ni], 0, 0, 0);
    }
  }
#pragma unroll
  for (int ni = 0; ni < 4; ++ni) {
    int col = bcol + wc * 64 + ni * 16 + l15;
    float bb = bias ? bias[col] : 0.f;
#pragma unroll
    for (int mi = 0; mi < 4; ++mi) {
      int row0 = brow + wr * 64 + mi * 16 + lhi * 4;
#pragma unroll
      for (int j = 0; j < 4; ++j) {
        int r = row0 + j;
        if (r >= M) continue;
        float val = acc[mi][ni][j] + bb;
        if (OUT_HALF) ((_Float16*)Cout)[(size_t)r * N + col] = (_Float16)val;
        else          ((float*)Cout)[(size_t)r * N + col] = val;
      }
    }
  }
}

// ---------------- fused prep: hist + W conversions + x->fp16 (block-specialized) ----------------
// blocks [0,1250): hist; [1250,3554): Wt_cat; [3554,5602): Wt_qk+bias; [5602,10602): xh
__global__ __launch_bounds__(256) void prep_k(
    const int* __restrict__ dst, const int* __restrict__ et, int* __restrict__ hist,
    const float* __restrict__ W_root, const float* __restrict__ W_rel,
    _Float16* __restrict__ Wt_cat,
    const float* __restrict__ Wq, const float* __restrict__ Wk,
    const float* __restrict__ Wv, const float* __restrict__ Ws,
    const float* __restrict__ bq, const float* __restrict__ bk,
    const float* __restrict__ bv, const float* __restrict__ bs,
    _Float16* __restrict__ Wt_qk, float* __restrict__ bias_cat,
    const float* __restrict__ x, _Float16* __restrict__ xh)
{
  int b = blockIdx.x, tid = threadIdx.x;
  if (b < 1250) {                               // edge histogram
    int e = b * 256 + tid;
    if (e < N_EDGES) atomicAdd(&hist[dst[e] * NREL + et[e]], 1);
  } else if (b < 3554) {                        // Wt_cat: 256 x 2304
    int idx = (b - 1250) * 256 + tid;           // < 589,824
    int k = idx % 2304, n = idx / 2304;
    float v = (k < 256) ? W_root[(size_t)k * H1DIM + n]
                        : W_rel[(size_t)(k - 256) * H1DIM + n];
    Wt_cat[(size_t)n * 2304 + k] = (_Float16)v;
  } else if (b < 5602) {                        // Wt_qk: 2048 x 256 (+ bias)
    int idx = (b - 3554) * 256 + tid;           // < 524,288
    int n = idx >> 8, k = idx & 255;
    int sel = n >> 9, c = n & 511;
    const float* W = sel == 0 ? Wq : sel == 1 ? Wk : sel == 2 ? Wv : Ws;
    Wt_qk[(size_t)n * 256 + k] = (_Float16)W[(size_t)k * C2DIM + c];
    if (k == 0) {
      const float* B = sel == 0 ? bq : sel == 1 ? bk : sel == 2 ? bv : bs;
      bias_cat[n] = B[c];
    }
  } else {                                      // x -> fp16, float4 granularity
    int i = (b - 5602) * 256 + tid;             // < 1,280,000
    float4 v = ((const float4*)x)[i];
    half4 o = {(_Float16)v.x, (_Float16)v.y, (_Float16)v.z, (_Float16)v.w};
    ((half4*)xh)[i] = o;
  }
}

// ---------------- hierarchical exclusive scan ----------------
__global__ __launch_bounds__(1024) void scan_local_k(
    const int* __restrict__ in, int* __restrict__ out, int* __restrict__ bsum, int n)
{
  __shared__ int s[1024];
  int gi = blockIdx.x * 1024 + threadIdx.x;
  int v = gi < n ? in[gi] : 0;
  s[threadIdx.x] = v; __syncthreads();
  for (int off = 1; off < 1024; off <<= 1) {
    int t = threadIdx.x >= off ? s[threadIdx.x - off] : 0;
    __syncthreads();
    s[threadIdx.x] += t;
    __syncthreads();
  }
  if (gi < n) out[gi] = s[threadIdx.x] - v;
  if (threadIdx.x == 1023) bsum[blockIdx.x] = s[1023];
}

__global__ __launch_bounds__(1024) void scan_small_k(int* __restrict__ bsum, int nb)
{
  __shared__ int s[1024];
  int v = threadIdx.x < nb ? bsum[threadIdx.x] : 0;
  s[threadIdx.x] = v; __syncthreads();
  for (int off = 1; off < 1024; off <<= 1) {
    int t = threadIdx.x >= off ? s[threadIdx.x - off] : 0;
    __syncthreads();
    s[threadIdx.x] += t;
    __syncthreads();
  }
  if (threadIdx.x < nb) bsum[threadIdx.x] = s[threadIdx.x] - v;
}

// addoff + cursor init + sentinel (replaces initcur_k)
__global__ void scan_addoff_k(int* __restrict__ off, const int* __restrict__ bsum,
                              int* __restrict__ cur, int n)
{
  int gi = blockIdx.x * 1024 + threadIdx.x;
  if (gi < n) {
    int v = off[gi] + bsum[blockIdx.x];
    off[gi] = v;
    cur[gi] = v;
  }
  if (gi == 0) off[n] = N_EDGES;
}

__global__ void reorder_k(const int* __restrict__ src, const int* __restrict__ dst,
                          const int* __restrict__ et,
                          int* __restrict__ cur, int* __restrict__ esrc)
{
  int e = blockIdx.x * blockDim.x + threadIdx.x;
  if (e >= N_EDGES) return;
  int seg = dst[e] * NREL + et[e];
  esrc[atomicAdd(&cur[seg], 1)] = src[e];
}

// ---------------- build Xcat = [x | mean_r(x)] in fp16 ----------------
__global__ __launch_bounds__(256) void agg_xcat_k(
    const _Float16* __restrict__ xh, const int* __restrict__ off,
    const int* __restrict__ esrc, _Float16* __restrict__ Xcat)
{
  int d = blockIdx.x * 4 + (threadIdx.x >> 6);
  if (d >= N_NODES) return;
  int lane = threadIdx.x & 63;
  _Float16* xrow = Xcat + (size_t)d * 2304;
  half4 xv = ((const half4*)(xh + (size_t)d * GDIM))[lane];
  *(half4*)(xrow + lane * 4) = xv;
  for (int r = 0; r < NREL; ++r) {
    int seg = d * NREL + r;
    int beg = off[seg], end = off[seg + 1];
    float4 acc = make_float4(0.f, 0.f, 0.f, 0.f);
    for (int e = beg; e < end; ++e) {
      int s = esrc[e];
      half4 v = ((const half4*)(xh + (size_t)s * GDIM))[lane];
      acc.x += (float)v.x; acc.y += (float)v.y;
      acc.z += (float)v.z; acc.w += (float)v.w;
    }
    float inv = (end > beg) ? 1.0f / (float)(end - beg) : 0.0f;
    half4 o;
    o.x = (_Float16)(acc.x * inv); o.y = (_Float16)(acc.y * inv);
    o.z = (_Float16)(acc.z * inv); o.w = (_Float16)(acc.w * inv);
    *(half4*)(xrow + 256 + r * 256 + lane * 4) = o;
  }
}

// ---------------- fused attention: QKVS row = [q|k|v|skip] fp16, N x 2048 ----------------
__global__ __launch_bounds__(256) void attn_fused_k(
    const _Float16* __restrict__ qkvs,
    const int* __restrict__ off, const int* __restrict__ esrc,
    float* __restrict__ out)
{
  int d = blockIdx.x * 4 + (threadIdx.x >> 6);
  if (d >= N_NODES) return;
  int lane = threadIdx.x & 63;
  half8 qr = ((const half8*)(qkvs + (size_t)d * 2048))[lane];
  float qf[8];
#pragma unroll
  for (int j = 0; j < 8; ++j) qf[j] = (float)qr[j];
  float m = -3.4e38f, ssum = 0.f;
  float av[8] = {};
  int beg = off[d * NREL], end = off[d * NREL + NREL];
  half8 krN = {}, vrN = {};
  if (beg < end) {
    int s0 = esrc[beg];
    const half8* row = (const half8*)(qkvs + (size_t)s0 * 2048 + 512);
    krN = row[lane];        // k: cols 512..1023
    vrN = row[64 + lane];   // v: cols 1024..1535 (contiguous with k)
  }
  for (int e = beg; e < end; ++e) {
    half8 kr = krN, vr = vrN;
    if (e + 1 < end) {
      int s1 = esrc[e + 1];
      const half8* row = (const half8*)(qkvs + (size_t)s1 * 2048 + 512);
      krN = row[lane];
      vrN = row[64 + lane];
    }
    float p = 0.f;
#pragma unroll
    for (int j = 0; j < 8; ++j) p += qf[j] * (float)kr[j];
    p += __shfl_xor(p, 1); p += __shfl_xor(p, 2);
    p += __shfl_xor(p, 4); p += __shfl_xor(p, 8);
    float a = p * 0.08838834764831845f;      // 1/sqrt(128)
    float mn = fmaxf(m, a);
    float corr = __expf(m - mn), w = __expf(a - mn);
    ssum = ssum * corr + w;
#pragma unroll
    for (int j = 0; j < 8; ++j) av[j] = av[j] * corr + w * (float)vr[j];
    m = mn;
  }
  float inv = 1.0f / fmaxf(ssum, 1e-16f);
  half8 sr = ((const half8*)(qkvs + (size_t)d * 2048 + 1536))[lane];  // skip
  float* orow = out + (size_t)d * C2DIM + lane * 8;
#pragma unroll
  for (int j = 0; j < 8; ++j) orow[j] = av[j] * inv + (float)sr[j];
}

// ---------------- BN ----------------
__global__ __launch_bounds__(512) void bn_stats_k(
    const float* __restrict__ x, float* __restrict__ sums, float* __restrict__ sumsq)
{
  int c = threadIdx.x;
  float s = 0.f, sq = 0.f;
  for (int row = blockIdx.x; row < N_NODES; row += gridDim.x) {
    float v = x[(size_t)row * C2DIM + c];
    s += v; sq += v * v;
  }
  atomicAdd(&sums[c], s);
  atomicAdd(&sumsq[c], sq);
}

// apply with inline scale/shift computation (bn_final folded in)
__global__ void bn_apply_k(float* __restrict__ x,
                           const float* __restrict__ sums, const float* __restrict__ sumsq,
                           const float* __restrict__ gamma, const float* __restrict__ beta,
                           int total4)
{
  int i = blockIdx.x * blockDim.x + threadIdx.x;
  if (i >= total4) return;
  int c0 = (i & 127) * 4;
  float4 v = ((const float4*)x)[i];
  float o[4] = {v.x, v.y, v.z, v.w};
#pragma unroll
  for (int j = 0; j < 4; ++j) {
    int c = c0 + j;
    float mu  = sums[c] * (1.0f / N_NODES);
    float var = sumsq[c] * (1.0f / N_NODES) - mu * mu;
    float sc  = gamma[c] * rsqrtf(var + 1e-5f);
    float val = (o[j] - mu) * sc + beta[c];
    o[j] = val >= 0.f ? val : 0.01f * val;
  }
  ((float4*)x)[i] = make_float4(o[0], o[1], o[2], o[3]);
}

// ---------------- launch ----------------
extern "C" void kernel_launch(void* const* d_in, const int* in_sizes, int n_in,
                              void* d_out, int out_size, void* d_ws, size_t ws_size,
                              hipStream_t stream)
{
  const float* x      = (const float*)d_in[0];
  const int*   ei     = (const int*)d_in[2];
  const int*   src    = ei;
  const int*   dst    = ei + N_EDGES;
  const int*   etype  = (const int*)d_in[3];
  const float* W_rel  = (const float*)d_in[4];
  const float* W_root = (const float*)d_in[5];
  const float* b_rgcn = (const float*)d_in[6];
  const float* W_q = (const float*)d_in[7];  const float* b_q = (const float*)d_in[8];
  const float* W_k = (const float*)d_in[9];  const float* b_k = (const float*)d_in[10];
  const float* W_v = (const float*)d_in[11]; const float* b_v = (const float*)d_in[12];
  const float* W_s = (const float*)d_in[13]; const float* b_s = (const float*)d_in[14];
  const float* gamma = (const float*)d_in[15];
  const float* beta  = (const float*)d_in[16];
  float* out = (float*)d_out;

  // ---- workspace layout ----
  char* ws = (char*)d_ws;
  _Float16* Xcat   = (_Float16*)(ws + 0);          // N x 2304 fp16 = 92,160,000
  _Float16* QKVS   = (_Float16*)(ws + 0);          // reuse: N x 2048 fp16 = 81,920,000
  _Float16* Wt_cat = (_Float16*)(ws + 92160000);   // 256 x 2304 fp16 = 1,179,648
  _Float16* Wt_qk  = (_Float16*)(ws + 93339648);   // 2048 x 256 fp16 = 1,048,576
  _Float16* h1h    = (_Float16*)(ws + 94388224);   // N x 256 fp16 = 10,240,000
  _Float16* xh     = h1h;                          // xh aliases h1h (dead before h1 GEMM)

  char* C = ws + 104628224;                    // CSR + small area
  int*   cur      = (int*)(C + 0);             // 640,000  (hist, then cursor)
  float* bns      = (float*)(C + 640000);      // 8,192  (contiguous with hist for 1 memset)
  float* bias_cat = (float*)(C + 648192);      // 8,192
  int*   off      = (int*)(C + 656384);        // 640,016
  int*   esrc     = (int*)(C + 1296400);       // 1,280,000
  int*   bsum     = (int*)(C + 2576400);       // 4,096  (ends 107,208,720)
  float* bnsum = bns, *bnsq = bns + 512;

  hipMemsetAsync(C, 0, 648192, stream);        // hist + bns in one call

  dim3 blk(256);
  const int NB = (NSEG + 1023) / 1024;         // 157

  // ---- fused prep: hist + weight conversions + x->fp16 ----
  prep_k<<<dim3(10602), blk, 0, stream>>>(
      dst, etype, cur,
      W_root, W_rel, Wt_cat,
      W_q, W_k, W_v, W_s, b_q, b_k, b_v, b_s, Wt_qk, bias_cat,
      x, xh);

  // ---- CSR scan + reorder ----
  scan_local_k<<<dim3(NB), dim3(1024), 0, stream>>>(cur, off, bsum, NSEG);
  scan_small_k<<<dim3(1), dim3(1024), 0, stream>>>(bsum, NB);
  scan_addoff_k<<<dim3(NB), dim3(1024), 0, stream>>>(off, bsum, cur, NSEG);
  reorder_k<<<dim3((N_EDGES + 255) / 256), blk, 0, stream>>>(
      src, dst, etype, cur, esrc);

  // ---- Xcat = [x | mean_r(x)] ----
  agg_xcat_k<<<dim3((N_NODES + 3) / 4), blk, 0, stream>>>(xh, off, esrc, Xcat);

  // ---- h1 (fp16) = Xcat @ Wcat + b_rgcn : K=2304 GEMM ----
  gemm_mfma_k<1><<<dim3(H1DIM / 128, (N_NODES + 127) / 128), blk, 0, stream>>>(
      Xcat, Wt_cat, b_rgcn, h1h, N_NODES, H1DIM, 2304);

  // ---- QKVS (fp16, N=2048 = [q|k|v|skip]) = h1 @ Wt_qk + bias_cat ----
  gemm_mfma_k<1><<<dim3(2048 / 128, (N_NODES + 127) / 128), blk, 0, stream>>>(
      h1h, Wt_qk, bias_cat, QKVS, N_NODES, 2048, 256);

  // ---- fused attention: out = attn(q,k,v) + skip ----
  attn_fused_k<<<dim3((N_NODES + 3) / 4), blk, 0, stream>>>(QKVS, off, esrc, out);

  // ---- BatchNorm + LeakyReLU (in place on d_out) ----
  bn_stats_k<<<dim3(208), dim3(512), 0, stream>>>(out, bnsum, bnsq);
  bn_apply_k<<<dim3((N_NODES * C2DIM / 4 + 255) / 256), blk, 0, stream>>>(
      out, bnsum, bnsq, gamma, beta, N_NODES * C2DIM / 4);
}